// Round 1
// baseline (1291.546 us; speedup 1.0000x reference)
//
#include <hip/hip_runtime.h>
#include <hip/hip_fp16.h>
#include <math.h>

#define TOK 2048      // B*S
#define HD 2048       // hidden
#define VOC 32000
#define BM 128
#define BN 128
#define BK 64
#define NCH (VOC/64)  // 500 col-chunks of 64
#define KSTEPS (HD/BK)
#define NBLK ((TOK/BM)*(VOC/BN))  // 4000

typedef _Float16 half8 __attribute__((ext_vector_type(8)));
typedef float float4v __attribute__((ext_vector_type(4)));

// C = X * W^T + bias, but only per-row (max, sum-exp) over 64-col chunks,
// plus optional total-logit sum. f16 MFMA 16x16x32, 128x128 tile, BK=64.
__global__ __launch_bounds__(256) void gemm_stats(
    const float* __restrict__ X, const float* __restrict__ W,
    const float* __restrict__ bias,
    float* __restrict__ pmax, float* __restrict__ psum,
    float* __restrict__ bsum, int computeSum)
{
  __shared__ unsigned char lds[BM*BK*2 + BN*BK*2];  // 16KB A + 16KB B (f16)
  unsigned char* ldsA = lds;
  unsigned char* ldsB = lds + BM*BK*2;

  // XCD-aware swizzle: 4000 blocks, 8 XCDs, 500 per XCD (bijective).
  int bid = blockIdx.x;
  int swz = (bid & 7) * (NBLK/8) + (bid >> 3);
  int rowt = swz & 15;        // 16 row tiles (fast axis: share W panel)
  int colt = swz >> 4;        // 250 col tiles

  int tid  = threadIdx.x;
  int lane = tid & 63;
  int wv   = tid >> 6;
  int wrow = wv >> 1, wcol = wv & 1;

  int brow = rowt * BM;
  int bcol = colt * BN;

  float4v acc[4][4];
  for (int m=0;m<4;m++) for(int n=0;n<4;n++) acc[m][n] = (float4v){0.f,0.f,0.f,0.f};

  int r0 = tid >> 3;            // 0..31
  int c8 = (tid & 7) * 8;       // float col start within BK
  const float* gA = X + (size_t)(brow + r0) * HD + c8;
  const float* gB = W + (size_t)(bcol + r0) * HD + c8;

  for (int ks=0; ks<KSTEPS; ks++) {
    int k0 = ks * BK;
    __syncthreads();
    // --- stage: global fp32 -> cvt f16 -> LDS (XOR-swizzled rows) ---
    #pragma unroll
    for (int it=0; it<4; it++) {
      int row = it*32 + r0;
      const float* pa = gA + (size_t)it*32*HD + k0;
      const float* pb = gB + (size_t)it*32*HD + k0;
      float4v fa0 = *(const float4v*)(pa);
      float4v fa1 = *(const float4v*)(pa + 4);
      float4v fb0 = *(const float4v*)(pb);
      float4v fb1 = *(const float4v*)(pb + 4);
      half8 ha, hb;
      #pragma unroll
      for (int j=0;j<4;j++) {
        ha[j]   = (_Float16)fa0[j];
        ha[4+j] = (_Float16)fa1[j];
        hb[j]   = (_Float16)fb0[j];
        hb[4+j] = (_Float16)fb1[j];
      }
      int byt = row*128 + ((c8*2) ^ ((row&7)<<4));
      *(half8*)(ldsA + byt) = ha;
      *(half8*)(ldsB + byt) = hb;
    }
    __syncthreads();
    // --- compute: 2 k-chunks x 4x4 fragments ---
    #pragma unroll
    for (int kk=0; kk<2; kk++) {
      half8 af[4], bf[4];
      int kb = kk*64 + ((lane>>4)*16);
      #pragma unroll
      for (int m=0;m<4;m++) {
        int row = wrow*64 + m*16 + (lane&15);
        af[m] = *(const half8*)(ldsA + row*128 + (kb ^ ((row&7)<<4)));
      }
      #pragma unroll
      for (int n=0;n<4;n++) {
        int row = wcol*64 + n*16 + (lane&15);
        bf[n] = *(const half8*)(ldsB + row*128 + (kb ^ ((row&7)<<4)));
      }
      #pragma unroll
      for (int m=0;m<4;m++)
        #pragma unroll
        for (int n=0;n<4;n++)
          acc[m][n] = __builtin_amdgcn_mfma_f32_16x16x32_f16(af[m], bf[n], acc[m][n], 0,0,0);
    }
  }

  // --- epilogue: bias, per-row max & sum-exp over this wave's 64 cols ---
  float bv[4];
  #pragma unroll
  for (int n=0;n<4;n++) bv[n] = bias[bcol + wcol*64 + n*16 + (lane&15)];

  float lsum = 0.f;
  #pragma unroll
  for (int m=0;m<4;m++) {
    #pragma unroll
    for (int r=0;r<4;r++) {
      float v0 = acc[m][0][r] + bv[0];
      float v1 = acc[m][1][r] + bv[1];
      float v2 = acc[m][2][r] + bv[2];
      float v3 = acc[m][3][r] + bv[3];
      if (computeSum) lsum += v0+v1+v2+v3;
      float mx = fmaxf(fmaxf(v0,v1), fmaxf(v2,v3));
      #pragma unroll
      for (int off=1; off<16; off<<=1) mx = fmaxf(mx, __shfl_xor(mx, off, 64));
      float se = __expf(v0-mx)+__expf(v1-mx)+__expf(v2-mx)+__expf(v3-mx);
      #pragma unroll
      for (int off=1; off<16; off<<=1) se += __shfl_xor(se, off, 64);
      if ((lane & 15) == 0) {
        int row = brow + wrow*64 + m*16 + (lane>>4)*4 + r;
        int ch  = colt*2 + wcol;
        pmax[(size_t)row*NCH + ch] = mx;
        psum[(size_t)row*NCH + ch] = se;
      }
    }
  }

  if (computeSum) {
    #pragma unroll
    for (int off=1; off<64; off<<=1) lsum += __shfl_xor(lsum, off, 64);
    __syncthreads();                 // LDS reads all done; safe to reuse
    float* red = (float*)lds;
    if (lane == 0) red[wv] = lsum;
    __syncthreads();
    if (tid == 0) bsum[blockIdx.x] = red[0]+red[1]+red[2]+red[3];
  }
}

// Per token-row: merge 500 chunk partials -> masked max-log-softmax.
__global__ void row_combine(const float* __restrict__ pmax,
                            const float* __restrict__ psum,
                            const float* __restrict__ mask,
                            float* __restrict__ tok)
{
  int row = blockIdx.x;
  int lane = threadIdx.x;   // 64
  float M = -INFINITY;
  for (int c = lane; c < NCH; c += 64) M = fmaxf(M, pmax[(size_t)row*NCH + c]);
  #pragma unroll
  for (int off=1; off<64; off<<=1) M = fmaxf(M, __shfl_xor(M, off, 64));
  float L = 0.f;
  for (int c = lane; c < NCH; c += 64)
    L += psum[(size_t)row*NCH + c] * __expf(pmax[(size_t)row*NCH + c] - M);
  #pragma unroll
  for (int off=1; off<64; off<<=1) L += __shfl_xor(L, off, 64);
  if (lane == 0) tok[row] = -logf(L) * mask[row];
}

// Single block: sequence sums, GRPO scalars, 5 outputs.
__global__ void finalize(const float* __restrict__ tokP,
                         const float* __restrict__ tokR,
                         const float* __restrict__ rewards,
                         const float* __restrict__ bsum, int nbsum,
                         float* __restrict__ out)
{
  __shared__ float red[256];
  __shared__ float seqP[4], seqR[4];
  int t = threadIdx.x;
  for (int b=0; b<4; b++) {
    float v = tokP[b*512 + t] + tokP[b*512 + 256 + t];
    red[t] = v; __syncthreads();
    for (int s=128; s>0; s>>=1) { if (t < s) red[t] += red[t+s]; __syncthreads(); }
    if (t == 0) seqP[b] = red[0];
    __syncthreads();
    v = tokR[b*512 + t] + tokR[b*512 + 256 + t];
    red[t] = v; __syncthreads();
    for (int s=128; s>0; s>>=1) { if (t < s) red[t] += red[t+s]; __syncthreads(); }
    if (t == 0) seqR[b] = red[0];
    __syncthreads();
  }
  float ls = 0.f;
  for (int i=t; i<nbsum; i+=256) ls += bsum[i];
  red[t] = ls; __syncthreads();
  for (int s=128; s>0; s>>=1) { if (t < s) red[t] += red[t+s]; __syncthreads(); }
  if (t == 0) {
    float r0=rewards[0], r1=rewards[1], r2=rewards[2], r3=rewards[3];
    float rm = (r0+r1+r2+r3)*0.25f;
    float var = ((r0-rm)*(r0-rm)+(r1-rm)*(r1-rm)+(r2-rm)*(r2-rm)+(r3-rm)*(r3-rm))/3.f;
    float rstd = sqrtf(var);
    float adv[4] = {r0-rm, r1-rm, r2-rm, r3-rm};
    if (rstd > 0.f) { for (int b=0;b<4;b++) adv[b] /= rstd; }
    float loss=0.f, sm=0.f, km=0.f;
    for (int b=0;b<4;b++) {
      float kl = seqP[b] - seqR[b];
      loss += -(adv[b]*seqP[b]) + 0.1f*kl;
      sm += seqP[b]; km += kl;
    }
    loss *= 0.25f; sm *= 0.25f; km *= 0.25f;
    float sv = 0.f;
    for (int b=0;b<4;b++) { float d = seqP[b]-sm; sv += d*d; }
    float sstd = sqrtf(sv/3.f);
    out[0] = loss;
    out[1] = sm;
    out[2] = sstd;
    out[3] = red[0] / ((float)TOK * (float)VOC);
    out[4] = km;
  }
}

extern "C" void kernel_launch(void* const* d_in, const int* in_sizes, int n_in,
                              void* d_out, int out_size, void* d_ws, size_t ws_size,
                              hipStream_t stream) {
  const float* W    = (const float*)d_in[0];
  const float* X    = (const float*)d_in[1];
  const float* mask = (const float*)d_in[2];
  const float* rew  = (const float*)d_in[3];
  const float* bias = (const float*)d_in[4];
  const float* Xr   = (const float*)d_in[5];
  const float* Wr   = (const float*)d_in[6];
  const float* br   = (const float*)d_in[7];
  float* out = (float*)d_out;

  float* pmax = (float*)d_ws;                       // 2048*500
  float* psum = pmax + (size_t)TOK*NCH;             // 2048*500
  float* tokP = psum + (size_t)TOK*NCH;             // 2048
  float* tokR = tokP + TOK;                         // 2048
  float* bsum = tokR + TOK;                         // 4000

  gemm_stats<<<NBLK, 256, 0, stream>>>(X,  W,  bias, pmax, psum, bsum, 1);
  row_combine<<<TOK, 64, 0, stream>>>(pmax, psum, mask, tokP);
  gemm_stats<<<NBLK, 256, 0, stream>>>(Xr, Wr, br,   pmax, psum, bsum, 0);
  row_combine<<<TOK, 64, 0, stream>>>(pmax, psum, mask, tokR);
  finalize<<<1, 256, 0, stream>>>(tokP, tokR, rew, bsum, NBLK, out);
}

// Round 2
// 955.031 us; speedup vs baseline: 1.3524x; 1.3524x over previous
//
#include <hip/hip_runtime.h>
#include <hip/hip_fp16.h>
#include <math.h>

#define TOK 2048      // B*S
#define HD 2048       // hidden
#define VOC 32000
#define BM 128
#define BN 128
#define BK 64
#define NCH (VOC/64)  // 500 col-chunks of 64
#define KSTEPS (HD/BK)
#define NBLK ((TOK/BM)*(VOC/BN))  // 4000

typedef _Float16 half8 __attribute__((ext_vector_type(8)));
typedef float float4v __attribute__((ext_vector_type(4)));

#define GLB __attribute__((address_space(1)))
#define LDS __attribute__((address_space(3)))

static __device__ __forceinline__ void gload_lds16(const void* g, void* l) {
  __builtin_amdgcn_global_load_lds((const GLB unsigned int*)g,
                                   (LDS unsigned int*)l, 16, 0, 0);
}

// ---------- fp32 -> f16 convert (memory-bound, vectorized) ----------
__global__ void cvt_f32_f16(const float* __restrict__ in,
                            _Float16* __restrict__ out, int n8) {
  for (int i = blockIdx.x * blockDim.x + threadIdx.x; i < n8;
       i += gridDim.x * blockDim.x) {
    float4v a = *(const float4v*)(in + (size_t)i*8);
    float4v b = *(const float4v*)(in + (size_t)i*8 + 4);
    half8 h;
    #pragma unroll
    for (int j=0;j<4;j++) { h[j] = (_Float16)a[j]; h[4+j] = (_Float16)b[j]; }
    *(half8*)(out + (size_t)i*8) = h;
  }
}

// ---------- m97-structure GEMM: f16 inputs, global_load_lds(16B) ----------
// C = X*W^T + bias; emits per-row (max,sumexp) over 64-col chunks + opt sum.
__global__ __launch_bounds__(256) void gemm_stats_f16(
    const _Float16* __restrict__ Xh, const _Float16* __restrict__ Wh,
    const float* __restrict__ bias,
    float* __restrict__ pmax, float* __restrict__ psum,
    float* __restrict__ bsum, int computeSum)
{
  __shared__ unsigned char lds[BM*BK*2 + BN*BK*2];  // 16KB A + 16KB B
  unsigned char* ldsA = lds;
  unsigned char* ldsB = lds + BM*BK*2;

  int bid = blockIdx.x;
  int swz = (bid & 7) * (NBLK/8) + (bid >> 3);   // XCD-aware, bijective
  int rowt = swz & 15;
  int colt = swz >> 4;

  int tid  = threadIdx.x;
  int lane = tid & 63;
  int wv   = tid >> 6;
  int wrow = wv >> 1, wcol = wv & 1;

  int brow = rowt * BM;
  int bcol = colt * BN;

  float4v acc[4][4];
  for (int m=0;m<4;m++) for(int n=0;n<4;n++) acc[m][n] = (float4v){0.f,0.f,0.f,0.f};

  // staging geometry: per wave, 4 chunks of 8 rows x 128B for A and B.
  int srow = (lane >> 3);            // 0..7 within chunk
  int scol = (lane & 7) * 16;        // 16B chunk within 128B row
  const unsigned char* gA = (const unsigned char*)Xh;
  const unsigned char* gB = (const unsigned char*)Wh;

  for (int ks=0; ks<KSTEPS; ks++) {
    size_t kbyte = (size_t)ks * (BK*2);
    __syncthreads();
    #pragma unroll
    for (int c=0;c<4;c++) {
      int row = wv*32 + c*8 + srow;
      int col = scol ^ ((row & 7) << 4);   // inverse-swizzled SOURCE
      gload_lds16(gA + (size_t)(brow + row)*(HD*2) + kbyte + col,
                  ldsA + (wv*32 + c*8)*128);
      gload_lds16(gB + (size_t)(bcol + row)*(HD*2) + kbyte + col,
                  ldsB + (wv*32 + c*8)*128);
    }
    __syncthreads();
    #pragma unroll
    for (int kk=0; kk<2; kk++) {
      half8 af[4], bf[4];
      int kb = kk*64 + ((lane>>4)*16);
      #pragma unroll
      for (int m=0;m<4;m++) {
        int row = wrow*64 + m*16 + (lane&15);
        af[m] = *(const half8*)(ldsA + row*128 + (kb ^ ((row&7)<<4)));
      }
      #pragma unroll
      for (int n=0;n<4;n++) {
        int row = wcol*64 + n*16 + (lane&15);
        bf[n] = *(const half8*)(ldsB + row*128 + (kb ^ ((row&7)<<4)));
      }
      #pragma unroll
      for (int m=0;m<4;m++)
        #pragma unroll
        for (int n=0;n<4;n++)
          acc[m][n] = __builtin_amdgcn_mfma_f32_16x16x32_f16(af[m], bf[n], acc[m][n], 0,0,0);
    }
  }

  float bv[4];
  #pragma unroll
  for (int n=0;n<4;n++) bv[n] = bias[bcol + wcol*64 + n*16 + (lane&15)];

  float lsum = 0.f;
  #pragma unroll
  for (int m=0;m<4;m++) {
    #pragma unroll
    for (int r=0;r<4;r++) {
      float v0 = acc[m][0][r] + bv[0];
      float v1 = acc[m][1][r] + bv[1];
      float v2 = acc[m][2][r] + bv[2];
      float v3 = acc[m][3][r] + bv[3];
      if (computeSum) lsum += v0+v1+v2+v3;
      float mx = fmaxf(fmaxf(v0,v1), fmaxf(v2,v3));
      #pragma unroll
      for (int off=1; off<16; off<<=1) mx = fmaxf(mx, __shfl_xor(mx, off, 64));
      float se = __expf(v0-mx)+__expf(v1-mx)+__expf(v2-mx)+__expf(v3-mx);
      #pragma unroll
      for (int off=1; off<16; off<<=1) se += __shfl_xor(se, off, 64);
      if ((lane & 15) == 0) {
        int row = brow + wrow*64 + m*16 + (lane>>4)*4 + r;
        int ch  = colt*2 + wcol;
        pmax[(size_t)row*NCH + ch] = mx;
        psum[(size_t)row*NCH + ch] = se;
      }
    }
  }

  if (computeSum) {
    #pragma unroll
    for (int off=1; off<64; off<<=1) lsum += __shfl_xor(lsum, off, 64);
    __syncthreads();
    float* red = (float*)lds;
    if (lane == 0) red[wv] = lsum;
    __syncthreads();
    if (tid == 0) bsum[blockIdx.x] = red[0]+red[1]+red[2]+red[3];
  }
}

// ---------- fallback (R1): fp32 in, reg-staged cvt ----------
__global__ __launch_bounds__(256) void gemm_stats(
    const float* __restrict__ X, const float* __restrict__ W,
    const float* __restrict__ bias,
    float* __restrict__ pmax, float* __restrict__ psum,
    float* __restrict__ bsum, int computeSum)
{
  __shared__ unsigned char lds[BM*BK*2 + BN*BK*2];
  unsigned char* ldsA = lds;
  unsigned char* ldsB = lds + BM*BK*2;

  int bid = blockIdx.x;
  int swz = (bid & 7) * (NBLK/8) + (bid >> 3);
  int rowt = swz & 15;
  int colt = swz >> 4;

  int tid  = threadIdx.x;
  int lane = tid & 63;
  int wv   = tid >> 6;
  int wrow = wv >> 1, wcol = wv & 1;

  int brow = rowt * BM;
  int bcol = colt * BN;

  float4v acc[4][4];
  for (int m=0;m<4;m++) for(int n=0;n<4;n++) acc[m][n] = (float4v){0.f,0.f,0.f,0.f};

  int r0 = tid >> 3;
  int c8 = (tid & 7) * 8;
  const float* gA = X + (size_t)(brow + r0) * HD + c8;
  const float* gB = W + (size_t)(bcol + r0) * HD + c8;

  for (int ks=0; ks<KSTEPS; ks++) {
    int k0 = ks * BK;
    __syncthreads();
    #pragma unroll
    for (int it=0; it<4; it++) {
      int row = it*32 + r0;
      const float* pa = gA + (size_t)it*32*HD + k0;
      const float* pb = gB + (size_t)it*32*HD + k0;
      float4v fa0 = *(const float4v*)(pa);
      float4v fa1 = *(const float4v*)(pa + 4);
      float4v fb0 = *(const float4v*)(pb);
      float4v fb1 = *(const float4v*)(pb + 4);
      half8 ha, hb;
      #pragma unroll
      for (int j=0;j<4;j++) {
        ha[j]   = (_Float16)fa0[j];
        ha[4+j] = (_Float16)fa1[j];
        hb[j]   = (_Float16)fb0[j];
        hb[4+j] = (_Float16)fb1[j];
      }
      int byt = row*128 + ((c8*2) ^ ((row&7)<<4));
      *(half8*)(ldsA + byt) = ha;
      *(half8*)(ldsB + byt) = hb;
    }
    __syncthreads();
    #pragma unroll
    for (int kk=0; kk<2; kk++) {
      half8 af[4], bf[4];
      int kb = kk*64 + ((lane>>4)*16);
      #pragma unroll
      for (int m=0;m<4;m++) {
        int row = wrow*64 + m*16 + (lane&15);
        af[m] = *(const half8*)(ldsA + row*128 + (kb ^ ((row&7)<<4)));
      }
      #pragma unroll
      for (int n=0;n<4;n++) {
        int row = wcol*64 + n*16 + (lane&15);
        bf[n] = *(const half8*)(ldsB + row*128 + (kb ^ ((row&7)<<4)));
      }
      #pragma unroll
      for (int m=0;m<4;m++)
        #pragma unroll
        for (int n=0;n<4;n++)
          acc[m][n] = __builtin_amdgcn_mfma_f32_16x16x32_f16(af[m], bf[n], acc[m][n], 0,0,0);
    }
  }

  float bv[4];
  #pragma unroll
  for (int n=0;n<4;n++) bv[n] = bias[bcol + wcol*64 + n*16 + (lane&15)];

  float lsum = 0.f;
  #pragma unroll
  for (int m=0;m<4;m++) {
    #pragma unroll
    for (int r=0;r<4;r++) {
      float v0 = acc[m][0][r] + bv[0];
      float v1 = acc[m][1][r] + bv[1];
      float v2 = acc[m][2][r] + bv[2];
      float v3 = acc[m][3][r] + bv[3];
      if (computeSum) lsum += v0+v1+v2+v3;
      float mx = fmaxf(fmaxf(v0,v1), fmaxf(v2,v3));
      #pragma unroll
      for (int off=1; off<16; off<<=1) mx = fmaxf(mx, __shfl_xor(mx, off, 64));
      float se = __expf(v0-mx)+__expf(v1-mx)+__expf(v2-mx)+__expf(v3-mx);
      #pragma unroll
      for (int off=1; off<16; off<<=1) se += __shfl_xor(se, off, 64);
      if ((lane & 15) == 0) {
        int row = brow + wrow*64 + m*16 + (lane>>4)*4 + r;
        int ch  = colt*2 + wcol;
        pmax[(size_t)row*NCH + ch] = mx;
        psum[(size_t)row*NCH + ch] = se;
      }
    }
  }

  if (computeSum) {
    #pragma unroll
    for (int off=1; off<64; off<<=1) lsum += __shfl_xor(lsum, off, 64);
    __syncthreads();
    float* red = (float*)lds;
    if (lane == 0) red[wv] = lsum;
    __syncthreads();
    if (tid == 0) bsum[blockIdx.x] = red[0]+red[1]+red[2]+red[3];
  }
}

// ---------- per-row combine ----------
__global__ void row_combine(const float* __restrict__ pmax,
                            const float* __restrict__ psum,
                            const float* __restrict__ mask,
                            float* __restrict__ tok)
{
  int row = blockIdx.x;
  int lane = threadIdx.x;
  float M = -INFINITY;
  for (int c = lane; c < NCH; c += 64) M = fmaxf(M, pmax[(size_t)row*NCH + c]);
  #pragma unroll
  for (int off=1; off<64; off<<=1) M = fmaxf(M, __shfl_xor(M, off, 64));
  float L = 0.f;
  for (int c = lane; c < NCH; c += 64)
    L += psum[(size_t)row*NCH + c] * __expf(pmax[(size_t)row*NCH + c] - M);
  #pragma unroll
  for (int off=1; off<64; off<<=1) L += __shfl_xor(L, off, 64);
  if (lane == 0) tok[row] = -logf(L) * mask[row];
}

// ---------- finalize ----------
__global__ void finalize(const float* __restrict__ tokP,
                         const float* __restrict__ tokR,
                         const float* __restrict__ rewards,
                         const float* __restrict__ bsum, int nbsum,
                         float* __restrict__ out)
{
  __shared__ float red[256];
  __shared__ float seqP[4], seqR[4];
  int t = threadIdx.x;
  for (int b=0; b<4; b++) {
    float v = tokP[b*512 + t] + tokP[b*512 + 256 + t];
    red[t] = v; __syncthreads();
    for (int s=128; s>0; s>>=1) { if (t < s) red[t] += red[t+s]; __syncthreads(); }
    if (t == 0) seqP[b] = red[0];
    __syncthreads();
    v = tokR[b*512 + t] + tokR[b*512 + 256 + t];
    red[t] = v; __syncthreads();
    for (int s=128; s>0; s>>=1) { if (t < s) red[t] += red[t+s]; __syncthreads(); }
    if (t == 0) seqR[b] = red[0];
    __syncthreads();
  }
  float ls = 0.f;
  for (int i=t; i<nbsum; i+=256) ls += bsum[i];
  red[t] = ls; __syncthreads();
  for (int s=128; s>0; s>>=1) { if (t < s) red[t] += red[t+s]; __syncthreads(); }
  if (t == 0) {
    float r0=rewards[0], r1=rewards[1], r2=rewards[2], r3=rewards[3];
    float rm = (r0+r1+r2+r3)*0.25f;
    float var = ((r0-rm)*(r0-rm)+(r1-rm)*(r1-rm)+(r2-rm)*(r2-rm)+(r3-rm)*(r3-rm))/3.f;
    float rstd = sqrtf(var);
    float adv[4] = {r0-rm, r1-rm, r2-rm, r3-rm};
    if (rstd > 0.f) { for (int b=0;b<4;b++) adv[b] /= rstd; }
    float loss=0.f, sm=0.f, km=0.f;
    for (int b=0;b<4;b++) {
      float kl = seqP[b] - seqR[b];
      loss += -(adv[b]*seqP[b]) + 0.1f*kl;
      sm += seqP[b]; km += kl;
    }
    loss *= 0.25f; sm *= 0.25f; km *= 0.25f;
    float sv = 0.f;
    for (int b=0;b<4;b++) { float d = seqP[b]-sm; sv += d*d; }
    float sstd = sqrtf(sv/3.f);
    out[0] = loss;
    out[1] = sm;
    out[2] = sstd;
    out[3] = red[0] / ((float)TOK * (float)VOC);
    out[4] = km;
  }
}

extern "C" void kernel_launch(void* const* d_in, const int* in_sizes, int n_in,
                              void* d_out, int out_size, void* d_ws, size_t ws_size,
                              hipStream_t stream) {
  const float* W    = (const float*)d_in[0];
  const float* X    = (const float*)d_in[1];
  const float* mask = (const float*)d_in[2];
  const float* rew  = (const float*)d_in[3];
  const float* bias = (const float*)d_in[4];
  const float* Xr   = (const float*)d_in[5];
  const float* Wr   = (const float*)d_in[6];
  const float* br   = (const float*)d_in[7];
  float* out = (float*)d_out;

  float* pmax = (float*)d_ws;                       // 2048*500
  float* psum = pmax + (size_t)TOK*NCH;             // 2048*500
  float* tokP = psum + (size_t)TOK*NCH;             // 2048
  float* tokR = tokP + TOK;                         // 2048
  float* bsum = tokR + TOK;                         // 4096 (pad)

  size_t headFloats = (size_t)TOK*NCH*2 + TOK*2 + 4096;
  size_t offXh = headFloats * 4;                    // bytes, 16B-aligned
  size_t xhBytes = (size_t)TOK*HD*2;
  size_t whBytes = (size_t)VOC*HD*2;
  size_t need = offXh + xhBytes + whBytes;

  if (ws_size >= need) {
    _Float16* Xh = (_Float16*)((unsigned char*)d_ws + offXh);
    _Float16* Wh = (_Float16*)((unsigned char*)d_ws + offXh + xhBytes);

    cvt_f32_f16<<<2048, 256, 0, stream>>>(X,  Xh, TOK*HD/8);
    cvt_f32_f16<<<2048, 256, 0, stream>>>(W,  Wh, VOC*HD/8);
    gemm_stats_f16<<<NBLK, 256, 0, stream>>>(Xh, Wh, bias, pmax, psum, bsum, 1);
    row_combine<<<TOK, 64, 0, stream>>>(pmax, psum, mask, tokP);
    cvt_f32_f16<<<2048, 256, 0, stream>>>(Xr, Xh, TOK*HD/8);
    cvt_f32_f16<<<2048, 256, 0, stream>>>(Wr, Wh, VOC*HD/8);
    gemm_stats_f16<<<NBLK, 256, 0, stream>>>(Xh, Wh, br, pmax, psum, bsum, 0);
    row_combine<<<TOK, 64, 0, stream>>>(pmax, psum, mask, tokR);
    finalize<<<1, 256, 0, stream>>>(tokP, tokR, rew, bsum, NBLK, out);
  } else {
    gemm_stats<<<NBLK, 256, 0, stream>>>(X,  W,  bias, pmax, psum, bsum, 1);
    row_combine<<<TOK, 64, 0, stream>>>(pmax, psum, mask, tokP);
    gemm_stats<<<NBLK, 256, 0, stream>>>(Xr, Wr, br,   pmax, psum, bsum, 0);
    row_combine<<<TOK, 64, 0, stream>>>(pmax, psum, mask, tokR);
    finalize<<<1, 256, 0, stream>>>(tokP, tokR, rew, bsum, NBLK, out);
  }
}

// Round 3
// 727.743 us; speedup vs baseline: 1.7747x; 1.3123x over previous
//
#include <hip/hip_runtime.h>
#include <hip/hip_fp16.h>
#include <math.h>

#define TOK 2048      // B*S
#define HD 2048       // hidden
#define VOC 32000
#define BM 256
#define BN 256
#define BK 64
#define NT (HD/BK)                // 32 K-tiles
#define NCH (VOC/64)              // 500 col-chunks of 64
#define NBLK ((TOK/BM)*(VOC/BN))  // 8*125 = 1000

typedef _Float16 half8 __attribute__((ext_vector_type(8)));
typedef float float4v __attribute__((ext_vector_type(4)));

#define GLB __attribute__((address_space(1)))
#define LDSAS __attribute__((address_space(3)))

static __device__ __forceinline__ void gload_lds16(const void* g, void* l) {
  __builtin_amdgcn_global_load_lds((const GLB unsigned int*)g,
                                   (LDSAS unsigned int*)l, 16, 0, 0);
}

// ---------- fp32 -> f16 convert (memory-bound, vectorized) ----------
__global__ void cvt_f32_f16(const float* __restrict__ in,
                            _Float16* __restrict__ out, int n8) {
  for (int i = blockIdx.x * blockDim.x + threadIdx.x; i < n8;
       i += gridDim.x * blockDim.x) {
    float4v a = *(const float4v*)(in + (size_t)i*8);
    float4v b = *(const float4v*)(in + (size_t)i*8 + 4);
    half8 h;
    #pragma unroll
    for (int j=0;j<4;j++) { h[j] = (_Float16)a[j]; h[4+j] = (_Float16)b[j]; }
    *(half8*)(out + (size_t)i*8) = h;
  }
}

// ---------- 256x256 8-phase GEMM with fused row stats ----------
// C = X*W^T + bias; emits per-row (max,sumexp) per 64-col chunk + opt. sum.
// LDS: 2 buffers x 4 units x 16KB. Units: u0=A(kk0) u1=B(kk0) u2=A(kk1) u3=B(kk1).
// Phase j of tile t: P0 reads u0(m0-3)+u1, stages (t+1,u2); P1 reads u0(m4-7),
// stages (t+1,u3); P2 reads u2(m0-3)+u3, stages (t+2,u0); P3 reads u2(m4-7),
// stages (t+2,u1), vmcnt(4). Every overwrite target's last ds_read is >=1
// barrier before the stage issue.
__global__ __launch_bounds__(512, 2) void gemm_stats_f16(
    const _Float16* __restrict__ Xh, const _Float16* __restrict__ Wh,
    const float* __restrict__ bias,
    float* __restrict__ pmax, float* __restrict__ psum,
    float* __restrict__ bsum, int computeSum)
{
  __shared__ unsigned char ldsbuf[131072];
  unsigned char* ldsby = ldsbuf;

  int bid = blockIdx.x;
  int swz = (bid & 7) * (NBLK/8) + (bid >> 3);   // XCD-aware, bijective (1000%8==0)
  int rowt = swz & 7;          // fast axis: 8 row tiles share W panel in L2
  int colt = swz >> 3;         // 125 col tiles
  int brow = rowt * BM;
  int bcol = colt * BN;

  int tid  = threadIdx.x;
  int lane = tid & 63;
  int wv   = tid >> 6;
  int wr   = wv >> 2;          // 0..1 (M)
  int wc   = wv & 3;           // 0..3 (N)
  int l15  = lane & 15;
  int q    = lane >> 4;

  // fragment LDS byte offsets within a unit (per-thread constants)
  // swizzle: slot c = (q + r + (r>>2)) & 3  -> 2 addrs per bank-quad (free)
  int aoff[8], boff[4];
  #pragma unroll
  for (int m = 0; m < 8; m++) {
    int r = wr*128 + m*16 + l15;
    aoff[m] = r*64 + (((q + r + (r>>2)) & 3) << 4);
  }
  #pragma unroll
  for (int n = 0; n < 4; n++) {
    int r = wc*64 + n*16 + l15;
    boff[n] = r*64 + (((q + r + (r>>2)) & 3) << 4);
  }

  // stage: 512 thr x 2 x 16B = 16KB/unit, linear LDS dest, inv-swizzled source
  int r0 = tid >> 2, c0 = tid & 3;
  int r1 = r0 + 128;
  int q0 = (c0 - r0 - (r0>>2)) & 3;
  int q1 = (c0 - r1 - (r1>>2)) & 3;
  int sA0 = (brow + r0)*(HD*2) + (q0<<4);
  int sA1 = (brow + r1)*(HD*2) + (q1<<4);
  int sB0 = (bcol + r0)*(HD*2) + (q0<<4);
  int sB1 = (bcol + r1)*(HD*2) + (q1<<4);
  int ldst0 = (wv<<10);          // wave-uniform LDS dest base, lane*16 auto
  int ldst1 = (wv<<10) + 8192;

  const char* Xb = (const char*)Xh;
  const char* Wb = (const char*)Wh;

  float4v acc[8][4];
  #pragma unroll
  for (int m=0;m<8;m++)
    #pragma unroll
    for (int n=0;n<4;n++) acc[m][n] = (float4v){0.f,0.f,0.f,0.f};

  auto stage = [&](int tile, int u) {
    int kb = (tile << 7) + ((u & 2) << 5);      // tile*128 + (u>>1)*64
    int db = ((tile & 1) << 16) + (u << 14);
    if (u & 1) {
      gload_lds16(Wb + sB0 + kb, ldsby + db + ldst0);
      gload_lds16(Wb + sB1 + kb, ldsby + db + ldst1);
    } else {
      gload_lds16(Xb + sA0 + kb, ldsby + db + ldst0);
      gload_lds16(Xb + sA1 + kb, ldsby + db + ldst1);
    }
  };

  // prologue: tile0 complete + tile1 u0,u1 -> 12 loads; wait until tile0 (8) landed
  stage(0,0); stage(0,1); stage(0,2); stage(0,3);
  stage(1,0); stage(1,1);
  asm volatile("s_waitcnt vmcnt(4)" ::: "memory");
  __builtin_amdgcn_sched_barrier(0);
  __builtin_amdgcn_s_barrier();
  __builtin_amdgcn_sched_barrier(0);

  half8 af[4], bf[4];

  for (int t = 0; t < NT; ++t) {
    int cb = (t & 1) << 16;
    // ---------------- P0: A(m0-3)+B @kk0 ----------------
    #pragma unroll
    for (int m=0;m<4;m++) af[m] = *(const half8*)(ldsby + cb + aoff[m]);
    #pragma unroll
    for (int n=0;n<4;n++) bf[n] = *(const half8*)(ldsby + cb + 16384 + boff[n]);
    if (t+1 < NT) stage(t+1, 2);
    __builtin_amdgcn_sched_barrier(0);
    __builtin_amdgcn_s_barrier();
    asm volatile("s_waitcnt lgkmcnt(0)" ::: "memory");
    __builtin_amdgcn_sched_barrier(0);
    __builtin_amdgcn_s_setprio(1);
    #pragma unroll
    for (int m=0;m<4;m++)
      #pragma unroll
      for (int n=0;n<4;n++)
        acc[m][n] = __builtin_amdgcn_mfma_f32_16x16x32_f16(af[m], bf[n], acc[m][n],0,0,0);
    __builtin_amdgcn_s_setprio(0);
    __builtin_amdgcn_sched_barrier(0);
    __builtin_amdgcn_s_barrier();
    __builtin_amdgcn_sched_barrier(0);
    // ---------------- P1: A(m4-7) @kk0 (B reused) ----------------
    #pragma unroll
    for (int m=0;m<4;m++) af[m] = *(const half8*)(ldsby + cb + aoff[4+m]);
    if (t+1 < NT) stage(t+1, 3);
    __builtin_amdgcn_sched_barrier(0);
    __builtin_amdgcn_s_barrier();
    asm volatile("s_waitcnt lgkmcnt(0)" ::: "memory");
    __builtin_amdgcn_sched_barrier(0);
    __builtin_amdgcn_s_setprio(1);
    #pragma unroll
    for (int m=0;m<4;m++)
      #pragma unroll
      for (int n=0;n<4;n++)
        acc[4+m][n] = __builtin_amdgcn_mfma_f32_16x16x32_f16(af[m], bf[n], acc[4+m][n],0,0,0);
    __builtin_amdgcn_s_setprio(0);
    __builtin_amdgcn_sched_barrier(0);
    __builtin_amdgcn_s_barrier();
    __builtin_amdgcn_sched_barrier(0);
    // ---------------- P2: A(m0-3)+B @kk1 ----------------
    #pragma unroll
    for (int m=0;m<4;m++) af[m] = *(const half8*)(ldsby + cb + 32768 + aoff[m]);
    #pragma unroll
    for (int n=0;n<4;n++) bf[n] = *(const half8*)(ldsby + cb + 49152 + boff[n]);
    if (t+2 < NT) stage(t+2, 0);
    __builtin_amdgcn_sched_barrier(0);
    __builtin_amdgcn_s_barrier();
    asm volatile("s_waitcnt lgkmcnt(0)" ::: "memory");
    __builtin_amdgcn_sched_barrier(0);
    __builtin_amdgcn_s_setprio(1);
    #pragma unroll
    for (int m=0;m<4;m++)
      #pragma unroll
      for (int n=0;n<4;n++)
        acc[m][n] = __builtin_amdgcn_mfma_f32_16x16x32_f16(af[m], bf[n], acc[m][n],0,0,0);
    __builtin_amdgcn_s_setprio(0);
    __builtin_amdgcn_sched_barrier(0);
    __builtin_amdgcn_s_barrier();
    __builtin_amdgcn_sched_barrier(0);
    // ---------------- P3: A(m4-7) @kk1 (B reused) ----------------
    #pragma unroll
    for (int m=0;m<4;m++) af[m] = *(const half8*)(ldsby + cb + 32768 + aoff[4+m]);
    if (t+2 < NT) stage(t+2, 1);
    __builtin_amdgcn_sched_barrier(0);
    __builtin_amdgcn_s_barrier();
    asm volatile("s_waitcnt lgkmcnt(0)" ::: "memory");
    __builtin_amdgcn_sched_barrier(0);
    __builtin_amdgcn_s_setprio(1);
    #pragma unroll
    for (int m=0;m<4;m++)
      #pragma unroll
      for (int n=0;n<4;n++)
        acc[4+m][n] = __builtin_amdgcn_mfma_f32_16x16x32_f16(af[m], bf[n], acc[4+m][n],0,0,0);
    __builtin_amdgcn_s_setprio(0);
    // counted vmcnt: next tile fully landed; 2 half-tiles (4 loads) stay in flight
    if (t + 2 < NT) asm volatile("s_waitcnt vmcnt(4)" ::: "memory");
    else            asm volatile("s_waitcnt vmcnt(0)" ::: "memory");
    __builtin_amdgcn_sched_barrier(0);
    __builtin_amdgcn_s_barrier();
    __builtin_amdgcn_sched_barrier(0);
  }

  // ---------------- epilogue: bias + per-row max/sumexp ----------------
  float bv[4];
  #pragma unroll
  for (int n=0;n<4;n++) bv[n] = bias[bcol + wc*64 + n*16 + l15];

  float lsum = 0.f;
  int ch = colt*4 + wc;
  #pragma unroll
  for (int m=0;m<8;m++) {
    #pragma unroll
    for (int r=0;r<4;r++) {
      float v0 = acc[m][0][r] + bv[0];
      float v1 = acc[m][1][r] + bv[1];
      float v2 = acc[m][2][r] + bv[2];
      float v3 = acc[m][3][r] + bv[3];
      if (computeSum) lsum += v0+v1+v2+v3;
      float mx = fmaxf(fmaxf(v0,v1), fmaxf(v2,v3));
      #pragma unroll
      for (int off=1; off<16; off<<=1) mx = fmaxf(mx, __shfl_xor(mx, off, 64));
      float se = __expf(v0-mx)+__expf(v1-mx)+__expf(v2-mx)+__expf(v3-mx);
      #pragma unroll
      for (int off=1; off<16; off<<=1) se += __shfl_xor(se, off, 64);
      if (l15 == 0) {
        int row = brow + wr*128 + m*16 + (lane>>4)*4 + r;
        pmax[(size_t)row*NCH + ch] = mx;
        psum[(size_t)row*NCH + ch] = se;
      }
    }
  }

  if (computeSum) {
    #pragma unroll
    for (int off=1; off<64; off<<=1) lsum += __shfl_xor(lsum, off, 64);
    __syncthreads();
    float* red = (float*)ldsbuf;
    if (lane == 0) red[wv] = lsum;
    __syncthreads();
    if (tid == 0) {
      float s = 0.f;
      for (int w=0; w<8; w++) s += red[w];
      bsum[blockIdx.x] = s;
    }
  }
}

// ---------- per-row combine ----------
__global__ void row_combine(const float* __restrict__ pmax,
                            const float* __restrict__ psum,
                            const float* __restrict__ mask,
                            float* __restrict__ tok)
{
  int row = blockIdx.x;
  int lane = threadIdx.x;
  float M = -INFINITY;
  for (int c = lane; c < NCH; c += 64) M = fmaxf(M, pmax[(size_t)row*NCH + c]);
  #pragma unroll
  for (int off=1; off<64; off<<=1) M = fmaxf(M, __shfl_xor(M, off, 64));
  float L = 0.f;
  for (int c = lane; c < NCH; c += 64)
    L += psum[(size_t)row*NCH + c] * __expf(pmax[(size_t)row*NCH + c] - M);
  #pragma unroll
  for (int off=1; off<64; off<<=1) L += __shfl_xor(L, off, 64);
  if (lane == 0) tok[row] = -logf(L) * mask[row];
}

// ---------- finalize ----------
__global__ void finalize(const float* __restrict__ tokP,
                         const float* __restrict__ tokR,
                         const float* __restrict__ rewards,
                         const float* __restrict__ bsum, int nbsum,
                         float* __restrict__ out)
{
  __shared__ float red[256];
  __shared__ float seqP[4], seqR[4];
  int t = threadIdx.x;
  for (int b=0; b<4; b++) {
    float v = tokP[b*512 + t] + tokP[b*512 + 256 + t];
    red[t] = v; __syncthreads();
    for (int s=128; s>0; s>>=1) { if (t < s) red[t] += red[t+s]; __syncthreads(); }
    if (t == 0) seqP[b] = red[0];
    __syncthreads();
    v = tokR[b*512 + t] + tokR[b*512 + 256 + t];
    red[t] = v; __syncthreads();
    for (int s=128; s>0; s>>=1) { if (t < s) red[t] += red[t+s]; __syncthreads(); }
    if (t == 0) seqR[b] = red[0];
    __syncthreads();
  }
  float ls = 0.f;
  for (int i=t; i<nbsum; i+=256) ls += bsum[i];
  red[t] = ls; __syncthreads();
  for (int s=128; s>0; s>>=1) { if (t < s) red[t] += red[t+s]; __syncthreads(); }
  if (t == 0) {
    float r0=rewards[0], r1=rewards[1], r2=rewards[2], r3=rewards[3];
    float rm = (r0+r1+r2+r3)*0.25f;
    float var = ((r0-rm)*(r0-rm)+(r1-rm)*(r1-rm)+(r2-rm)*(r2-rm)+(r3-rm)*(r3-rm))/3.f;
    float rstd = sqrtf(var);
    float adv[4] = {r0-rm, r1-rm, r2-rm, r3-rm};
    if (rstd > 0.f) { for (int b=0;b<4;b++) adv[b] /= rstd; }
    float loss=0.f, sm=0.f, km=0.f;
    for (int b=0;b<4;b++) {
      float kl = seqP[b] - seqR[b];
      loss += -(adv[b]*seqP[b]) + 0.1f*kl;
      sm += seqP[b]; km += kl;
    }
    loss *= 0.25f; sm *= 0.25f; km *= 0.25f;
    float sv = 0.f;
    for (int b=0;b<4;b++) { float d = seqP[b]-sm; sv += d*d; }
    float sstd = sqrtf(sv/3.f);
    out[0] = loss;
    out[1] = sm;
    out[2] = sstd;
    out[3] = red[0] / ((float)TOK * (float)VOC);
    out[4] = km;
  }
}

extern "C" void kernel_launch(void* const* d_in, const int* in_sizes, int n_in,
                              void* d_out, int out_size, void* d_ws, size_t ws_size,
                              hipStream_t stream) {
  const float* W    = (const float*)d_in[0];
  const float* X    = (const float*)d_in[1];
  const float* mask = (const float*)d_in[2];
  const float* rew  = (const float*)d_in[3];
  const float* bias = (const float*)d_in[4];
  const float* Xr   = (const float*)d_in[5];
  const float* Wr   = (const float*)d_in[6];
  const float* br   = (const float*)d_in[7];
  float* out = (float*)d_out;

  float* pmax = (float*)d_ws;                       // 2048*500
  float* psum = pmax + (size_t)TOK*NCH;             // 2048*500
  float* tokP = psum + (size_t)TOK*NCH;             // 2048
  float* tokR = tokP + TOK;                         // 2048
  float* bsum = tokR + TOK;                         // 4096 (pad)

  size_t headFloats = (size_t)TOK*NCH*2 + TOK*2 + 4096;
  size_t offXh = headFloats * 4;
  _Float16* Xh = (_Float16*)((unsigned char*)d_ws + offXh);
  _Float16* Wh = (_Float16*)((unsigned char*)d_ws + offXh + (size_t)TOK*HD*2);

  cvt_f32_f16<<<2048, 256, 0, stream>>>(X,  Xh, TOK*HD/8);
  cvt_f32_f16<<<2048, 256, 0, stream>>>(W,  Wh, VOC*HD/8);
  gemm_stats_f16<<<NBLK, 512, 0, stream>>>(Xh, Wh, bias, pmax, psum, bsum, 1);
  row_combine<<<TOK, 64, 0, stream>>>(pmax, psum, mask, tokP);
  cvt_f32_f16<<<2048, 256, 0, stream>>>(Xr, Xh, TOK*HD/8);
  cvt_f32_f16<<<2048, 256, 0, stream>>>(Wr, Wh, VOC*HD/8);
  gemm_stats_f16<<<NBLK, 512, 0, stream>>>(Xh, Wh, br, pmax, psum, bsum, 0);
  row_combine<<<TOK, 64, 0, stream>>>(pmax, psum, mask, tokR);
  finalize<<<1, 256, 0, stream>>>(tokP, tokR, rew, bsum, NBLK, out);
}

// Round 4
// 718.125 us; speedup vs baseline: 1.7985x; 1.0134x over previous
//
#include <hip/hip_runtime.h>
#include <hip/hip_fp16.h>
#include <math.h>

#define TOK 2048      // B*S
#define HD 2048       // hidden
#define VOC 32000
#define BM 256
#define BN 256
#define BK 64
#define NT (HD/BK)                // 32 K-tiles
#define NCH (VOC/64)              // 500 col-chunks of 64
#define NBLK ((TOK/BM)*(VOC/BN))  // 8*125 = 1000

typedef _Float16 half8 __attribute__((ext_vector_type(8)));
typedef float float4v __attribute__((ext_vector_type(4)));

#define GLB __attribute__((address_space(1)))
#define LDSAS __attribute__((address_space(3)))

static __device__ __forceinline__ void gload_lds16(const void* g, void* l) {
  __builtin_amdgcn_global_load_lds((const GLB unsigned int*)g,
                                   (LDSAS unsigned int*)l, 16, 0, 0);
}

// ---------- fp32 -> f16 convert (memory-bound, vectorized) ----------
__global__ void cvt_f32_f16(const float* __restrict__ in,
                            _Float16* __restrict__ out, int n8) {
  for (int i = blockIdx.x * blockDim.x + threadIdx.x; i < n8;
       i += gridDim.x * blockDim.x) {
    float4v a = *(const float4v*)(in + (size_t)i*8);
    float4v b = *(const float4v*)(in + (size_t)i*8 + 4);
    half8 h;
    #pragma unroll
    for (int j=0;j<4;j++) { h[j] = (_Float16)a[j]; h[4+j] = (_Float16)b[j]; }
    *(half8*)(out + (size_t)i*8) = h;
  }
}

// One K-tile = 4 phases. Units (16KB each): u0=A kk0, u1=B kk0, u2=A kk1, u3=B kk1.
// Phase j of tile t stages: P0->(t+1,u2), P1->(t+1,u3), P2->(t+2,u0), P3->(t+2,u1).
// vmcnt(4) at end of P3 => tile t+1 fully landed, 4 loads (t+2 u0,u1) in flight.
// CB = compile-time LDS buffer byte base (0 or 65536). Only sched_barrier kept:
// post-lgkmcnt(0) (rule: MFMA hoists past inline-asm waitcnt otherwise).
template<int CB, bool SG01, bool SG23, int VMN>
__device__ __forceinline__ void ktile(
    unsigned char* ldsby, const char* Xb, const char* Wb,
    int sA0, int sA1, int sB0, int sB1, int ldst0, int ldst1, int kbn,
    const int (&aofs)[2][8], const int (&bofs)[2][4], float4v (&acc)[8][4])
{
  constexpr int BI = CB ? 1 : 0;
  half8 af[4], bf[4];

  // ---------------- P0: A(m0-3)+B @kk0; stage (t+1,u2)=A kk1 ----------------
  #pragma unroll
  for (int m=0;m<4;m++) af[m] = *(const half8*)(ldsby + aofs[BI][m]);
  #pragma unroll
  for (int n=0;n<4;n++) bf[n] = *(const half8*)(ldsby + bofs[BI][n] + 16384);
  if (SG01) {
    gload_lds16(Xb + (sA0 + kbn + 64), ldsby + ((CB^65536) + 32768) + ldst0);
    gload_lds16(Xb + (sA1 + kbn + 64), ldsby + ((CB^65536) + 32768) + ldst1);
  }
  __builtin_amdgcn_s_barrier();
  asm volatile("s_waitcnt lgkmcnt(0)" ::: "memory");
  __builtin_amdgcn_sched_barrier(0);
  __builtin_amdgcn_s_setprio(1);
  #pragma unroll
  for (int m=0;m<4;m++)
    #pragma unroll
    for (int n=0;n<4;n++)
      acc[m][n] = __builtin_amdgcn_mfma_f32_16x16x32_f16(af[m], bf[n], acc[m][n],0,0,0);
  __builtin_amdgcn_s_setprio(0);
  __builtin_amdgcn_s_barrier();

  // ---------------- P1: A(m4-7) @kk0 (B reused); stage (t+1,u3)=B kk1 -------
  #pragma unroll
  for (int m=0;m<4;m++) af[m] = *(const half8*)(ldsby + aofs[BI][4+m]);
  if (SG01) {
    gload_lds16(Wb + (sB0 + kbn + 64), ldsby + ((CB^65536) + 49152) + ldst0);
    gload_lds16(Wb + (sB1 + kbn + 64), ldsby + ((CB^65536) + 49152) + ldst1);
  }
  __builtin_amdgcn_s_barrier();
  asm volatile("s_waitcnt lgkmcnt(0)" ::: "memory");
  __builtin_amdgcn_sched_barrier(0);
  __builtin_amdgcn_s_setprio(1);
  #pragma unroll
  for (int m=0;m<4;m++)
    #pragma unroll
    for (int n=0;n<4;n++)
      acc[4+m][n] = __builtin_amdgcn_mfma_f32_16x16x32_f16(af[m], bf[n], acc[4+m][n],0,0,0);
  __builtin_amdgcn_s_setprio(0);
  __builtin_amdgcn_s_barrier();

  // ---------------- P2: A(m0-3)+B @kk1; stage (t+2,u0)=A kk0 ----------------
  #pragma unroll
  for (int m=0;m<4;m++) af[m] = *(const half8*)(ldsby + aofs[BI][m] + 32768);
  #pragma unroll
  for (int n=0;n<4;n++) bf[n] = *(const half8*)(ldsby + bofs[BI][n] + 49152);
  if (SG23) {
    gload_lds16(Xb + (sA0 + kbn + 128), ldsby + (CB + 0) + ldst0);
    gload_lds16(Xb + (sA1 + kbn + 128), ldsby + (CB + 0) + ldst1);
  }
  __builtin_amdgcn_s_barrier();
  asm volatile("s_waitcnt lgkmcnt(0)" ::: "memory");
  __builtin_amdgcn_sched_barrier(0);
  __builtin_amdgcn_s_setprio(1);
  #pragma unroll
  for (int m=0;m<4;m++)
    #pragma unroll
    for (int n=0;n<4;n++)
      acc[m][n] = __builtin_amdgcn_mfma_f32_16x16x32_f16(af[m], bf[n], acc[m][n],0,0,0);
  __builtin_amdgcn_s_setprio(0);
  __builtin_amdgcn_s_barrier();

  // ---------------- P3: A(m4-7) @kk1 (B reused); stage (t+2,u1)=B kk0 -------
  #pragma unroll
  for (int m=0;m<4;m++) af[m] = *(const half8*)(ldsby + aofs[BI][4+m] + 32768);
  if (SG23) {
    gload_lds16(Wb + (sB0 + kbn + 128), ldsby + (CB + 16384) + ldst0);
    gload_lds16(Wb + (sB1 + kbn + 128), ldsby + (CB + 16384) + ldst1);
  }
  __builtin_amdgcn_s_barrier();
  asm volatile("s_waitcnt lgkmcnt(0)" ::: "memory");
  __builtin_amdgcn_sched_barrier(0);
  __builtin_amdgcn_s_setprio(1);
  #pragma unroll
  for (int m=0;m<4;m++)
    #pragma unroll
    for (int n=0;n<4;n++)
      acc[4+m][n] = __builtin_amdgcn_mfma_f32_16x16x32_f16(af[m], bf[n], acc[4+m][n],0,0,0);
  __builtin_amdgcn_s_setprio(0);
  if (VMN >= 0) {
    if (VMN == 4) asm volatile("s_waitcnt vmcnt(4)" ::: "memory");
    else          asm volatile("s_waitcnt vmcnt(0)" ::: "memory");
  }
  __builtin_amdgcn_s_barrier();
}

// ---------- 256x256 8-phase GEMM with fused row stats ----------
__global__ __launch_bounds__(512, 2) void gemm_stats_f16(
    const _Float16* __restrict__ Xh, const _Float16* __restrict__ Wh,
    const float* __restrict__ bias,
    float* __restrict__ pmax, float* __restrict__ psum,
    float* __restrict__ bsum, int computeSum)
{
  __shared__ unsigned char ldsbuf[131072];
  unsigned char* ldsby = ldsbuf;

  int bid = blockIdx.x;
  int swz = (bid & 7) * (NBLK/8) + (bid >> 3);   // XCD-aware, bijective (1000%8==0)
  int rowt = swz & 7;          // fast axis: 8 row tiles share W panel in L2
  int colt = swz >> 3;         // 125 col tiles
  int brow = rowt * BM;
  int bcol = colt * BN;

  int tid  = threadIdx.x;
  int lane = tid & 63;
  int wv   = tid >> 6;
  int wr   = wv >> 2;          // 0..1 (M)
  int wc   = wv & 3;           // 0..3 (N)
  int l15  = lane & 15;
  int q    = lane >> 4;

  // fragment LDS byte offsets within a unit, per buffer (CB baked in)
  int aofs[2][8], bofs[2][4];
  #pragma unroll
  for (int m = 0; m < 8; m++) {
    int r = wr*128 + m*16 + l15;
    int o = r*64 + (((q + r + (r>>2)) & 3) << 4);
    aofs[0][m] = o; aofs[1][m] = o + 65536;
  }
  #pragma unroll
  for (int n = 0; n < 4; n++) {
    int r = wc*64 + n*16 + l15;
    int o = r*64 + (((q + r + (r>>2)) & 3) << 4);
    bofs[0][n] = o; bofs[1][n] = o + 65536;
  }

  // staging geometry: dest linear (tid*16 within 16KB unit), source inv-swizzled
  int r0 = tid >> 2, c0 = tid & 3;
  int r1 = r0 + 128;
  int q0 = (c0 - r0 - (r0>>2)) & 3;
  int q1 = (c0 - r1 - (r1>>2)) & 3;
  int sA0 = (brow + r0)*(HD*2) + (q0<<4);
  int sA1 = (brow + r1)*(HD*2) + (q1<<4);
  int sB0 = (bcol + r0)*(HD*2) + (q0<<4);
  int sB1 = (bcol + r1)*(HD*2) + (q1<<4);
  int ldst0 = (wv<<10);          // wave-uniform LDS dest base (+lane*16 by HW)
  int ldst1 = (wv<<10) + 8192;

  const char* Xb = (const char*)Xh;
  const char* Wb = (const char*)Wh;

  float4v acc[8][4];
  #pragma unroll
  for (int m=0;m<8;m++)
    #pragma unroll
    for (int n=0;n<4;n++) acc[m][n] = (float4v){0.f,0.f,0.f,0.f};

  // prologue: tile0 u0..u3 + tile1 u0,u1
  gload_lds16(Xb + sA0,       ldsby + 0     + ldst0);
  gload_lds16(Xb + sA1,       ldsby + 0     + ldst1);
  gload_lds16(Wb + sB0,       ldsby + 16384 + ldst0);
  gload_lds16(Wb + sB1,       ldsby + 16384 + ldst1);
  gload_lds16(Xb + (sA0+64),  ldsby + 32768 + ldst0);
  gload_lds16(Xb + (sA1+64),  ldsby + 32768 + ldst1);
  gload_lds16(Wb + (sB0+64),  ldsby + 49152 + ldst0);
  gload_lds16(Wb + (sB1+64),  ldsby + 49152 + ldst1);
  gload_lds16(Xb + (sA0+128), ldsby + 65536 + ldst0);
  gload_lds16(Xb + (sA1+128), ldsby + 65536 + ldst1);
  gload_lds16(Wb + (sB0+128), ldsby + 81920 + ldst0);
  gload_lds16(Wb + (sB1+128), ldsby + 81920 + ldst1);
  asm volatile("s_waitcnt vmcnt(4)" ::: "memory");
  __builtin_amdgcn_s_barrier();

  int kbn = 128;   // byte k-offset of tile t+1 when processing tile t
  #pragma unroll 1
  for (int i = 0; i < 15; ++i) {
    ktile<0,     true, true, 4>(ldsby, Xb, Wb, sA0,sA1,sB0,sB1, ldst0,ldst1, kbn, aofs, bofs, acc);
    kbn += 128;
    ktile<65536, true, true, 4>(ldsby, Xb, Wb, sA0,sA1,sB0,sB1, ldst0,ldst1, kbn, aofs, bofs, acc);
    kbn += 128;
  }
  // tiles 30, 31
  ktile<0,     true,  false, 0>(ldsby, Xb, Wb, sA0,sA1,sB0,sB1, ldst0,ldst1, kbn, aofs, bofs, acc);
  kbn += 128;
  ktile<65536, false, false, -2>(ldsby, Xb, Wb, sA0,sA1,sB0,sB1, ldst0,ldst1, kbn, aofs, bofs, acc);

  // ---------------- epilogue: bias + per-row max/sumexp ----------------
  float bv[4];
  #pragma unroll
  for (int n=0;n<4;n++) bv[n] = bias[bcol + wc*64 + n*16 + l15];

  float lsum = 0.f;
  int ch = colt*4 + wc;
  #pragma unroll
  for (int m=0;m<8;m++) {
    #pragma unroll
    for (int r=0;r<4;r++) {
      float v0 = acc[m][0][r] + bv[0];
      float v1 = acc[m][1][r] + bv[1];
      float v2 = acc[m][2][r] + bv[2];
      float v3 = acc[m][3][r] + bv[3];
      if (computeSum) lsum += v0+v1+v2+v3;
      float mx = fmaxf(fmaxf(v0,v1), fmaxf(v2,v3));
      #pragma unroll
      for (int off=1; off<16; off<<=1) mx = fmaxf(mx, __shfl_xor(mx, off, 64));
      float se = __expf(v0-mx)+__expf(v1-mx)+__expf(v2-mx)+__expf(v3-mx);
      #pragma unroll
      for (int off=1; off<16; off<<=1) se += __shfl_xor(se, off, 64);
      if (l15 == 0) {
        int row = brow + wr*128 + m*16 + (lane>>4)*4 + r;
        pmax[(size_t)row*NCH + ch] = mx;
        psum[(size_t)row*NCH + ch] = se;
      }
    }
  }

  if (computeSum) {
    #pragma unroll
    for (int off=1; off<64; off<<=1) lsum += __shfl_xor(lsum, off, 64);
    __syncthreads();
    float* red = (float*)ldsbuf;
    if (lane == 0) red[wv] = lsum;
    __syncthreads();
    if (tid == 0) {
      float s = 0.f;
      for (int w=0; w<8; w++) s += red[w];
      bsum[blockIdx.x] = s;
    }
  }
}

// ---------- per-row combine ----------
__global__ void row_combine(const float* __restrict__ pmax,
                            const float* __restrict__ psum,
                            const float* __restrict__ mask,
                            float* __restrict__ tok)
{
  int row = blockIdx.x;
  int lane = threadIdx.x;
  float M = -INFINITY;
  for (int c = lane; c < NCH; c += 64) M = fmaxf(M, pmax[(size_t)row*NCH + c]);
  #pragma unroll
  for (int off=1; off<64; off<<=1) M = fmaxf(M, __shfl_xor(M, off, 64));
  float L = 0.f;
  for (int c = lane; c < NCH; c += 64)
    L += psum[(size_t)row*NCH + c] * __expf(pmax[(size_t)row*NCH + c] - M);
  #pragma unroll
  for (int off=1; off<64; off<<=1) L += __shfl_xor(L, off, 64);
  if (lane == 0) tok[row] = -logf(L) * mask[row];
}

// ---------- finalize ----------
__global__ void finalize(const float* __restrict__ tokP,
                         const float* __restrict__ tokR,
                         const float* __restrict__ rewards,
                         const float* __restrict__ bsum, int nbsum,
                         float* __restrict__ out)
{
  __shared__ float red[256];
  __shared__ float seqP[4], seqR[4];
  int t = threadIdx.x;
  for (int b=0; b<4; b++) {
    float v = tokP[b*512 + t] + tokP[b*512 + 256 + t];
    red[t] = v; __syncthreads();
    for (int s=128; s>0; s>>=1) { if (t < s) red[t] += red[t+s]; __syncthreads(); }
    if (t == 0) seqP[b] = red[0];
    __syncthreads();
    v = tokR[b*512 + t] + tokR[b*512 + 256 + t];
    red[t] = v; __syncthreads();
    for (int s=128; s>0; s>>=1) { if (t < s) red[t] += red[t+s]; __syncthreads(); }
    if (t == 0) seqR[b] = red[0];
    __syncthreads();
  }
  float ls = 0.f;
  for (int i=t; i<nbsum; i+=256) ls += bsum[i];
  red[t] = ls; __syncthreads();
  for (int s=128; s>0; s>>=1) { if (t < s) red[t] += red[t+s]; __syncthreads(); }
  if (t == 0) {
    float r0=rewards[0], r1=rewards[1], r2=rewards[2], r3=rewards[3];
    float rm = (r0+r1+r2+r3)*0.25f;
    float var = ((r0-rm)*(r0-rm)+(r1-rm)*(r1-rm)+(r2-rm)*(r2-rm)+(r3-rm)*(r3-rm))/3.f;
    float rstd = sqrtf(var);
    float adv[4] = {r0-rm, r1-rm, r2-rm, r3-rm};
    if (rstd > 0.f) { for (int b=0;b<4;b++) adv[b] /= rstd; }
    float loss=0.f, sm=0.f, km=0.f;
    for (int b=0;b<4;b++) {
      float kl = seqP[b] - seqR[b];
      loss += -(adv[b]*seqP[b]) + 0.1f*kl;
      sm += seqP[b]; km += kl;
    }
    loss *= 0.25f; sm *= 0.25f; km *= 0.25f;
    float sv = 0.f;
    for (int b=0;b<4;b++) { float d = seqP[b]-sm; sv += d*d; }
    float sstd = sqrtf(sv/3.f);
    out[0] = loss;
    out[1] = sm;
    out[2] = sstd;
    out[3] = red[0] / ((float)TOK * (float)VOC);
    out[4] = km;
  }
}

extern "C" void kernel_launch(void* const* d_in, const int* in_sizes, int n_in,
                              void* d_out, int out_size, void* d_ws, size_t ws_size,
                              hipStream_t stream) {
  const float* W    = (const float*)d_in[0];
  const float* X    = (const float*)d_in[1];
  const float* mask = (const float*)d_in[2];
  const float* rew  = (const float*)d_in[3];
  const float* bias = (const float*)d_in[4];
  const float* Xr   = (const float*)d_in[5];
  const float* Wr   = (const float*)d_in[6];
  const float* br   = (const float*)d_in[7];
  float* out = (float*)d_out;

  float* pmax = (float*)d_ws;                       // 2048*500
  float* psum = pmax + (size_t)TOK*NCH;             // 2048*500
  float* tokP = psum + (size_t)TOK*NCH;             // 2048
  float* tokR = tokP + TOK;                         // 2048
  float* bsum = tokR + TOK;                         // 4096 (pad)

  size_t headFloats = (size_t)TOK*NCH*2 + TOK*2 + 4096;
  size_t offXh = headFloats * 4;
  _Float16* Xh = (_Float16*)((unsigned char*)d_ws + offXh);
  _Float16* Wh = (_Float16*)((unsigned char*)d_ws + offXh + (size_t)TOK*HD*2);

  cvt_f32_f16<<<2048, 256, 0, stream>>>(X,  Xh, TOK*HD/8);
  cvt_f32_f16<<<2048, 256, 0, stream>>>(W,  Wh, VOC*HD/8);
  gemm_stats_f16<<<NBLK, 512, 0, stream>>>(Xh, Wh, bias, pmax, psum, bsum, 1);
  row_combine<<<TOK, 64, 0, stream>>>(pmax, psum, mask, tokP);
  cvt_f32_f16<<<2048, 256, 0, stream>>>(Xr, Xh, TOK*HD/8);
  cvt_f32_f16<<<2048, 256, 0, stream>>>(Wr, Wh, VOC*HD/8);
  gemm_stats_f16<<<NBLK, 512, 0, stream>>>(Xh, Wh, br, pmax, psum, bsum, 0);
  row_combine<<<TOK, 64, 0, stream>>>(pmax, psum, mask, tokR);
  finalize<<<1, 256, 0, stream>>>(tokP, tokR, rew, bsum, NBLK, out);
}

// Round 5
// 706.200 us; speedup vs baseline: 1.8289x; 1.0169x over previous
//
#include <hip/hip_runtime.h>
#include <hip/hip_fp16.h>
#include <math.h>

#define TOK 2048      // B*S
#define HD 2048       // hidden
#define VOC 32000
#define BM 256
#define BN 256
#define BK 64
#define NT (HD/BK)                // 32 K-tiles
#define NCH (VOC/64)              // 500 col-chunks of 64
#define NBLK ((TOK/BM)*(VOC/BN))  // 8*125 = 1000

typedef _Float16 half8 __attribute__((ext_vector_type(8)));
typedef float float4v __attribute__((ext_vector_type(4)));

#define GLB __attribute__((address_space(1)))
#define LDSAS __attribute__((address_space(3)))

static __device__ __forceinline__ void gload_lds16(const void* g, void* l) {
  __builtin_amdgcn_global_load_lds((const GLB unsigned int*)g,
                                   (LDSAS unsigned int*)l, 16, 0, 0);
}

// ---------- fp32 -> f16 convert (memory-bound, vectorized) ----------
__global__ void cvt_f32_f16(const float* __restrict__ in,
                            _Float16* __restrict__ out, int n8) {
  for (int i = blockIdx.x * blockDim.x + threadIdx.x; i < n8;
       i += gridDim.x * blockDim.x) {
    float4v a = *(const float4v*)(in + (size_t)i*8);
    float4v b = *(const float4v*)(in + (size_t)i*8 + 4);
    half8 h;
    #pragma unroll
    for (int j=0;j<4;j++) { h[j] = (_Float16)a[j]; h[4+j] = (_Float16)b[j]; }
    *(half8*)(out + (size_t)i*8) = h;
  }
}

// One K-tile = 2 phases, ONE trailing barrier each (mid-phase barriers removed:
// every stage's target unit had its last reader complete before the previous
// trailing barrier). Units (16KB): u0=A kk0, u1=B kk0, u2=A kk1, u3=B kk1.
// Phase A reads u0,u1; stages (t+1) u2,u3. Phase B reads u2,u3; stages (t+2)
// u0,u1; vmcnt(4) => tile t+1 fully landed, 4 loads (t+2 u0,u1) in flight.
template<int CB, bool SG1, bool SG2, int VMN>
__device__ __forceinline__ void ktile(
    unsigned char* ldsby, const char* Xb, const char* Wb,
    int sA0, int sA1, int sB0, int sB1, int ldst0, int ldst1, int kbn,
    const int (&aofs)[2][8], const int (&bofs)[2][4], float4v (&acc)[8][4])
{
  constexpr int BI = CB ? 1 : 0;
  half8 af[8], bf[4];

  // ================= Phase A: kk0 (u0,u1) =================
  #pragma unroll
  for (int n=0;n<4;n++) bf[n] = *(const half8*)(ldsby + bofs[BI][n] + 16384);
  #pragma unroll
  for (int m=0;m<8;m++) af[m] = *(const half8*)(ldsby + aofs[BI][m]);
  if (SG1) {   // stage (t+1) u2 = A kk1, u3 = B kk1 into other buffer
    gload_lds16(Xb + (sA0 + kbn + 64), ldsby + ((CB^65536) + 32768) + ldst0);
    gload_lds16(Xb + (sA1 + kbn + 64), ldsby + ((CB^65536) + 32768) + ldst1);
    gload_lds16(Wb + (sB0 + kbn + 64), ldsby + ((CB^65536) + 49152) + ldst0);
    gload_lds16(Wb + (sB1 + kbn + 64), ldsby + ((CB^65536) + 49152) + ldst1);
  }
  asm volatile("s_waitcnt lgkmcnt(4)" ::: "memory");  // bf + af[0..3] ready
  __builtin_amdgcn_sched_barrier(0);
  __builtin_amdgcn_s_setprio(1);
  #pragma unroll
  for (int m=0;m<4;m++)
    #pragma unroll
    for (int n=0;n<4;n++)
      acc[m][n] = __builtin_amdgcn_mfma_f32_16x16x32_f16(af[m], bf[n], acc[m][n],0,0,0);
  asm volatile("s_waitcnt lgkmcnt(0)" ::: "memory");  // af[4..7] ready
  __builtin_amdgcn_sched_barrier(0);
  #pragma unroll
  for (int m=4;m<8;m++)
    #pragma unroll
    for (int n=0;n<4;n++)
      acc[m][n] = __builtin_amdgcn_mfma_f32_16x16x32_f16(af[m], bf[n], acc[m][n],0,0,0);
  __builtin_amdgcn_s_setprio(0);
  __builtin_amdgcn_s_barrier();

  // ================= Phase B: kk1 (u2,u3) =================
  #pragma unroll
  for (int n=0;n<4;n++) bf[n] = *(const half8*)(ldsby + bofs[BI][n] + 49152);
  #pragma unroll
  for (int m=0;m<8;m++) af[m] = *(const half8*)(ldsby + aofs[BI][m] + 32768);
  if (SG2) {   // stage (t+2) u0 = A kk0, u1 = B kk0 into CURRENT buffer
    gload_lds16(Xb + (sA0 + kbn + 128), ldsby + (CB + 0)     + ldst0);
    gload_lds16(Xb + (sA1 + kbn + 128), ldsby + (CB + 0)     + ldst1);
    gload_lds16(Wb + (sB0 + kbn + 128), ldsby + (CB + 16384) + ldst0);
    gload_lds16(Wb + (sB1 + kbn + 128), ldsby + (CB + 16384) + ldst1);
  }
  asm volatile("s_waitcnt lgkmcnt(4)" ::: "memory");
  __builtin_amdgcn_sched_barrier(0);
  __builtin_amdgcn_s_setprio(1);
  #pragma unroll
  for (int m=0;m<4;m++)
    #pragma unroll
    for (int n=0;n<4;n++)
      acc[m][n] = __builtin_amdgcn_mfma_f32_16x16x32_f16(af[m], bf[n], acc[m][n],0,0,0);
  asm volatile("s_waitcnt lgkmcnt(0)" ::: "memory");
  __builtin_amdgcn_sched_barrier(0);
  #pragma unroll
  for (int m=4;m<8;m++)
    #pragma unroll
    for (int n=0;n<4;n++)
      acc[m][n] = __builtin_amdgcn_mfma_f32_16x16x32_f16(af[m], bf[n], acc[m][n],0,0,0);
  __builtin_amdgcn_s_setprio(0);
  if (VMN == 4)      asm volatile("s_waitcnt vmcnt(4)" ::: "memory");
  else if (VMN == 0) asm volatile("s_waitcnt vmcnt(0)" ::: "memory");
  __builtin_amdgcn_s_barrier();
}

// ---------- 256x256 2-phase/K-tile GEMM with fused row stats ----------
__global__ __launch_bounds__(512, 2) void gemm_stats_f16(
    const _Float16* __restrict__ Xh, const _Float16* __restrict__ Wh,
    const float* __restrict__ bias,
    float* __restrict__ pmax, float* __restrict__ psum,
    float* __restrict__ bsum, int computeSum)
{
  __shared__ unsigned char ldsbuf[131072];
  unsigned char* ldsby = ldsbuf;

  int bid = blockIdx.x;
  int swz = (bid & 7) * (NBLK/8) + (bid >> 3);   // XCD-aware, bijective (1000%8==0)
  int rowt = swz & 7;          // fast axis: 8 row tiles share W panel in L2
  int colt = swz >> 3;         // 125 col tiles
  int brow = rowt * BM;
  int bcol = colt * BN;

  int tid  = threadIdx.x;
  int lane = tid & 63;
  int wv   = tid >> 6;
  int wr   = wv >> 2;          // 0..1 (M)
  int wc   = wv & 3;           // 0..3 (N)
  int l15  = lane & 15;
  int q    = lane >> 4;

  // fragment LDS byte offsets within a unit, per buffer (CB baked in)
  int aofs[2][8], bofs[2][4];
  #pragma unroll
  for (int m = 0; m < 8; m++) {
    int r = wr*128 + m*16 + l15;
    int o = r*64 + (((q + r + (r>>2)) & 3) << 4);
    aofs[0][m] = o; aofs[1][m] = o + 65536;
  }
  #pragma unroll
  for (int n = 0; n < 4; n++) {
    int r = wc*64 + n*16 + l15;
    int o = r*64 + (((q + r + (r>>2)) & 3) << 4);
    bofs[0][n] = o; bofs[1][n] = o + 65536;
  }

  // staging geometry: dest linear (tid*16 within 16KB unit), source inv-swizzled
  int r0 = tid >> 2, c0 = tid & 3;
  int r1 = r0 + 128;
  int q0 = (c0 - r0 - (r0>>2)) & 3;
  int q1 = (c0 - r1 - (r1>>2)) & 3;
  int sA0 = (brow + r0)*(HD*2) + (q0<<4);
  int sA1 = (brow + r1)*(HD*2) + (q1<<4);
  int sB0 = (bcol + r0)*(HD*2) + (q0<<4);
  int sB1 = (bcol + r1)*(HD*2) + (q1<<4);
  int ldst0 = (wv<<10);          // wave-uniform LDS dest base (+lane*16 by HW)
  int ldst1 = (wv<<10) + 8192;

  const char* Xb = (const char*)Xh;
  const char* Wb = (const char*)Wh;

  float4v acc[8][4];
  #pragma unroll
  for (int m=0;m<8;m++)
    #pragma unroll
    for (int n=0;n<4;n++) acc[m][n] = (float4v){0.f,0.f,0.f,0.f};

  // prologue: tile0 u0..u3 + tile1 u0,u1 (12 loads), wait for tile0's 8
  gload_lds16(Xb + sA0,       ldsby + 0     + ldst0);
  gload_lds16(Xb + sA1,       ldsby + 0     + ldst1);
  gload_lds16(Wb + sB0,       ldsby + 16384 + ldst0);
  gload_lds16(Wb + sB1,       ldsby + 16384 + ldst1);
  gload_lds16(Xb + (sA0+64),  ldsby + 32768 + ldst0);
  gload_lds16(Xb + (sA1+64),  ldsby + 32768 + ldst1);
  gload_lds16(Wb + (sB0+64),  ldsby + 49152 + ldst0);
  gload_lds16(Wb + (sB1+64),  ldsby + 49152 + ldst1);
  gload_lds16(Xb + (sA0+128), ldsby + 65536 + ldst0);
  gload_lds16(Xb + (sA1+128), ldsby + 65536 + ldst1);
  gload_lds16(Wb + (sB0+128), ldsby + 81920 + ldst0);
  gload_lds16(Wb + (sB1+128), ldsby + 81920 + ldst1);
  asm volatile("s_waitcnt vmcnt(4)" ::: "memory");
  __builtin_amdgcn_s_barrier();

  int kbn = 128;   // byte k-offset of tile t+1 when processing tile t
  #pragma unroll 1
  for (int i = 0; i < 15; ++i) {
    ktile<0,     true, true, 4>(ldsby, Xb, Wb, sA0,sA1,sB0,sB1, ldst0,ldst1, kbn, aofs, bofs, acc);
    kbn += 128;
    ktile<65536, true, true, 4>(ldsby, Xb, Wb, sA0,sA1,sB0,sB1, ldst0,ldst1, kbn, aofs, bofs, acc);
    kbn += 128;
  }
  // tiles 30, 31
  ktile<0,     true,  false, 0>(ldsby, Xb, Wb, sA0,sA1,sB0,sB1, ldst0,ldst1, kbn, aofs, bofs, acc);
  kbn += 128;
  ktile<65536, false, false, -1>(ldsby, Xb, Wb, sA0,sA1,sB0,sB1, ldst0,ldst1, kbn, aofs, bofs, acc);

  // ---------------- epilogue: bias + per-row max/sumexp ----------------
  float bv[4];
  #pragma unroll
  for (int n=0;n<4;n++) bv[n] = bias[bcol + wc*64 + n*16 + l15];

  float lsum = 0.f;
  int ch = colt*4 + wc;
  #pragma unroll
  for (int m=0;m<8;m++) {
    #pragma unroll
    for (int r=0;r<4;r++) {
      float v0 = acc[m][0][r] + bv[0];
      float v1 = acc[m][1][r] + bv[1];
      float v2 = acc[m][2][r] + bv[2];
      float v3 = acc[m][3][r] + bv[3];
      if (computeSum) lsum += v0+v1+v2+v3;
      float mx = fmaxf(fmaxf(v0,v1), fmaxf(v2,v3));
      #pragma unroll
      for (int off=1; off<16; off<<=1) mx = fmaxf(mx, __shfl_xor(mx, off, 64));
      float se = __expf(v0-mx)+__expf(v1-mx)+__expf(v2-mx)+__expf(v3-mx);
      #pragma unroll
      for (int off=1; off<16; off<<=1) se += __shfl_xor(se, off, 64);
      if (l15 == 0) {
        int row = brow + wr*128 + m*16 + (lane>>4)*4 + r;
        pmax[(size_t)row*NCH + ch] = mx;
        psum[(size_t)row*NCH + ch] = se;
      }
    }
  }

  if (computeSum) {
    #pragma unroll
    for (int off=1; off<64; off<<=1) lsum += __shfl_xor(lsum, off, 64);
    __syncthreads();
    float* red = (float*)ldsbuf;
    if (lane == 0) red[wv] = lsum;
    __syncthreads();
    if (tid == 0) {
      float s = 0.f;
      for (int w=0; w<8; w++) s += red[w];
      bsum[blockIdx.x] = s;
    }
  }
}

// ---------- per-row combine ----------
__global__ void row_combine(const float* __restrict__ pmax,
                            const float* __restrict__ psum,
                            const float* __restrict__ mask,
                            float* __restrict__ tok)
{
  int row = blockIdx.x;
  int lane = threadIdx.x;
  float M = -INFINITY;
  for (int c = lane; c < NCH; c += 64) M = fmaxf(M, pmax[(size_t)row*NCH + c]);
  #pragma unroll
  for (int off=1; off<64; off<<=1) M = fmaxf(M, __shfl_xor(M, off, 64));
  float L = 0.f;
  for (int c = lane; c < NCH; c += 64)
    L += psum[(size_t)row*NCH + c] * __expf(pmax[(size_t)row*NCH + c] - M);
  #pragma unroll
  for (int off=1; off<64; off<<=1) L += __shfl_xor(L, off, 64);
  if (lane == 0) tok[row] = -logf(L) * mask[row];
}

// ---------- finalize ----------
__global__ void finalize(const float* __restrict__ tokP,
                         const float* __restrict__ tokR,
                         const float* __restrict__ rewards,
                         const float* __restrict__ bsum, int nbsum,
                         float* __restrict__ out)
{
  __shared__ float red[256];
  __shared__ float seqP[4], seqR[4];
  int t = threadIdx.x;
  for (int b=0; b<4; b++) {
    float v = tokP[b*512 + t] + tokP[b*512 + 256 + t];
    red[t] = v; __syncthreads();
    for (int s=128; s>0; s>>=1) { if (t < s) red[t] += red[t+s]; __syncthreads(); }
    if (t == 0) seqP[b] = red[0];
    __syncthreads();
    v = tokR[b*512 + t] + tokR[b*512 + 256 + t];
    red[t] = v; __syncthreads();
    for (int s=128; s>0; s>>=1) { if (t < s) red[t] += red[t+s]; __syncthreads(); }
    if (t == 0) seqR[b] = red[0];
    __syncthreads();
  }
  float ls = 0.f;
  for (int i=t; i<nbsum; i+=256) ls += bsum[i];
  red[t] = ls; __syncthreads();
  for (int s=128; s>0; s>>=1) { if (t < s) red[t] += red[t+s]; __syncthreads(); }
  if (t == 0) {
    float r0=rewards[0], r1=rewards[1], r2=rewards[2], r3=rewards[3];
    float rm = (r0+r1+r2+r3)*0.25f;
    float var = ((r0-rm)*(r0-rm)+(r1-rm)*(r1-rm)+(r2-rm)*(r2-rm)+(r3-rm)*(r3-rm))/3.f;
    float rstd = sqrtf(var);
    float adv[4] = {r0-rm, r1-rm, r2-rm, r3-rm};
    if (rstd > 0.f) { for (int b=0;b<4;b++) adv[b] /= rstd; }
    float loss=0.f, sm=0.f, km=0.f;
    for (int b=0;b<4;b++) {
      float kl = seqP[b] - seqR[b];
      loss += -(adv[b]*seqP[b]) + 0.1f*kl;
      sm += seqP[b]; km += kl;
    }
    loss *= 0.25f; sm *= 0.25f; km *= 0.25f;
    float sv = 0.f;
    for (int b=0;b<4;b++) { float d = seqP[b]-sm; sv += d*d; }
    float sstd = sqrtf(sv/3.f);
    out[0] = loss;
    out[1] = sm;
    out[2] = sstd;
    out[3] = red[0] / ((float)TOK * (float)VOC);
    out[4] = km;
  }
}

extern "C" void kernel_launch(void* const* d_in, const int* in_sizes, int n_in,
                              void* d_out, int out_size, void* d_ws, size_t ws_size,
                              hipStream_t stream) {
  const float* W    = (const float*)d_in[0];
  const float* X    = (const float*)d_in[1];
  const float* mask = (const float*)d_in[2];
  const float* rew  = (const float*)d_in[3];
  const float* bias = (const float*)d_in[4];
  const float* Xr   = (const float*)d_in[5];
  const float* Wr   = (const float*)d_in[6];
  const float* br   = (const float*)d_in[7];
  float* out = (float*)d_out;

  float* pmax = (float*)d_ws;                       // 2048*500
  float* psum = pmax + (size_t)TOK*NCH;             // 2048*500
  float* tokP = psum + (size_t)TOK*NCH;             // 2048
  float* tokR = tokP + TOK;                         // 2048
  float* bsum = tokR + TOK;                         // 4096 (pad)

  size_t headFloats = (size_t)TOK*NCH*2 + TOK*2 + 4096;
  size_t offXh = headFloats * 4;
  _Float16* Xh = (_Float16*)((unsigned char*)d_ws + offXh);
  _Float16* Wh = (_Float16*)((unsigned char*)d_ws + offXh + (size_t)TOK*HD*2);

  cvt_f32_f16<<<2048, 256, 0, stream>>>(X,  Xh, TOK*HD/8);
  cvt_f32_f16<<<2048, 256, 0, stream>>>(W,  Wh, VOC*HD/8);
  gemm_stats_f16<<<NBLK, 512, 0, stream>>>(Xh, Wh, bias, pmax, psum, bsum, 1);
  row_combine<<<TOK, 64, 0, stream>>>(pmax, psum, mask, tokP);
  cvt_f32_f16<<<2048, 256, 0, stream>>>(Xr, Xh, TOK*HD/8);
  cvt_f32_f16<<<2048, 256, 0, stream>>>(Wr, Wh, VOC*HD/8);
  gemm_stats_f16<<<NBLK, 512, 0, stream>>>(Xh, Wh, br, pmax, psum, bsum, 0);
  row_combine<<<TOK, 64, 0, stream>>>(pmax, psum, mask, tokR);
  finalize<<<1, 256, 0, stream>>>(tokP, tokR, rew, bsum, NBLK, out);
}

// Round 6
// 678.497 us; speedup vs baseline: 1.9035x; 1.0408x over previous
//
#include <hip/hip_runtime.h>
#include <hip/hip_fp16.h>
#include <math.h>

#define TOK 2048      // B*S
#define HD 2048       // hidden
#define VOC 32000
#define BM 256
#define BN 256
#define BK 64
#define NT (HD/BK)                // 32 K-tiles
#define NCH (VOC/64)              // 500 col-chunks of 64
#define NBLK ((TOK/BM)*(VOC/BN))  // 8*125 = 1000

typedef _Float16 half8 __attribute__((ext_vector_type(8)));
typedef float float4v __attribute__((ext_vector_type(4)));

#define GLB __attribute__((address_space(1)))
#define LDSAS __attribute__((address_space(3)))

static __device__ __forceinline__ void gload_lds16(const void* g, void* l) {
  __builtin_amdgcn_global_load_lds((const GLB unsigned int*)g,
                                   (LDSAS unsigned int*)l, 16, 0, 0);
}

static __device__ __forceinline__ float4v mfma16(half8 a, half8 b, float4v c) {
  return __builtin_amdgcn_mfma_f32_16x16x32_f16(a, b, c, 0, 0, 0);
}

// ---------- fp32 -> f16 convert (memory-bound, vectorized) ----------
__global__ void cvt_f32_f16(const float* __restrict__ in,
                            _Float16* __restrict__ out, int n8) {
  for (int i = blockIdx.x * blockDim.x + threadIdx.x; i < n8;
       i += gridDim.x * blockDim.x) {
    float4v a = *(const float4v*)(in + (size_t)i*8);
    float4v b = *(const float4v*)(in + (size_t)i*8 + 4);
    half8 h;
    #pragma unroll
    for (int j=0;j<4;j++) { h[j] = (_Float16)a[j]; h[4+j] = (_Float16)b[j]; }
    *(half8*)(out + (size_t)i*8) = h;
  }
}

// Units (16KB): u0=A kk0, u1=B kk0, u2=A kk1, u3=B kk1 (buffer stride 64KB).
// Unit-internal layout: 128 pairs x 128B; logical (row r, k-slot sk 0..3) at
// pair=r>>1, s=(r&1)*4+sk, byte = pair*128 + ((s ^ (pair&7))<<4)  [R2-proven
// conflict-free: 8 slots x 2-way]. Staged with linear LDS dest; the inverse
// permutation is applied to the per-lane GLOBAL source address.
// Schedule (R5): phase A computes kk0, stages (t+1) u2,u3 -> other buf;
// phase B computes kk1, stages (t+2) u0,u1 -> current buf; vmcnt(4) at tile
// end => t+1 fully landed, 4 loads (t+2 u0,u1) in flight. Phase B's fragment
// reads are PREFETCHED mid-phase-A (data resident; region re-staged only
// after next barrier).
template<int CB, bool SG1, bool SG2, int VMN>
__device__ __forceinline__ void ktile(
    unsigned char* ldsby, const char* Xb, const char* Wb,
    int sA0, int sA1, int sB0, int sB1, int ldst0, int ldst1, int kbn,
    const int (&aofs)[8], const int (&bofs)[4], float4v (&acc)[8][4])
{
  constexpr int U0 = CB, U1 = CB + 16384, U2 = CB + 32768, U3 = CB + 49152;
  half8 af1[8], bf1[4], af2lo[4], bf2[4], af2hi[4];

  // ================= Phase A: kk0 =================
  #pragma unroll
  for (int n=0;n<4;n++) bf1[n] = *(const half8*)(ldsby + U1 + bofs[n]);
  #pragma unroll
  for (int m=0;m<8;m++) af1[m] = *(const half8*)(ldsby + U0 + aofs[m]);
  if (SG1) {   // stage (t+1) u2 = A kk1, u3 = B kk1 into other buffer
    gload_lds16(Xb + (sA0 + kbn + 64), ldsby + ((CB^65536) + 32768) + ldst0);
    gload_lds16(Xb + (sA1 + kbn + 64), ldsby + ((CB^65536) + 32768) + ldst1);
    gload_lds16(Wb + (sB0 + kbn + 64), ldsby + ((CB^65536) + 49152) + ldst0);
    gload_lds16(Wb + (sB1 + kbn + 64), ldsby + ((CB^65536) + 49152) + ldst1);
  }
  __builtin_amdgcn_s_setprio(1);
  #pragma unroll
  for (int m=0;m<4;m++)
    #pragma unroll
    for (int n=0;n<4;n++)
      acc[m][n] = mfma16(af1[m], bf1[n], acc[m][n]);
  // prefetch phase-B fragments under the MFMA cluster
  #pragma unroll
  for (int n=0;n<4;n++) bf2[n]   = *(const half8*)(ldsby + U3 + bofs[n]);
  #pragma unroll
  for (int m=0;m<4;m++) af2lo[m] = *(const half8*)(ldsby + U2 + aofs[m]);
  #pragma unroll
  for (int m=4;m<8;m++)
    #pragma unroll
    for (int n=0;n<4;n++)
      acc[m][n] = mfma16(af1[m], bf1[n], acc[m][n]);
  __builtin_amdgcn_s_setprio(0);
  __builtin_amdgcn_s_barrier();

  // ================= Phase B: kk1 =================
  #pragma unroll
  for (int m=0;m<4;m++) af2hi[m] = *(const half8*)(ldsby + U2 + aofs[4+m]);
  if (SG2) {   // stage (t+2) u0 = A kk0, u1 = B kk0 into CURRENT buffer
    gload_lds16(Xb + (sA0 + kbn + 128), ldsby + (CB + 0)     + ldst0);
    gload_lds16(Xb + (sA1 + kbn + 128), ldsby + (CB + 0)     + ldst1);
    gload_lds16(Wb + (sB0 + kbn + 128), ldsby + (CB + 16384) + ldst0);
    gload_lds16(Wb + (sB1 + kbn + 128), ldsby + (CB + 16384) + ldst1);
  }
  __builtin_amdgcn_s_setprio(1);
  #pragma unroll
  for (int m=0;m<4;m++)
    #pragma unroll
    for (int n=0;n<4;n++)
      acc[m][n] = mfma16(af2lo[m], bf2[n], acc[m][n]);
  #pragma unroll
  for (int m=0;m<4;m++)
    #pragma unroll
    for (int n=0;n<4;n++)
      acc[4+m][n] = mfma16(af2hi[m], bf2[n], acc[4+m][n]);
  __builtin_amdgcn_s_setprio(0);
  if (VMN == 4)      asm volatile("s_waitcnt vmcnt(4)" ::: "memory");
  else if (VMN == 0) asm volatile("s_waitcnt vmcnt(0)" ::: "memory");
  __builtin_amdgcn_s_barrier();
}

// ---------- 256x256 2-phase/K-tile GEMM with fused row stats ----------
__global__ __launch_bounds__(512, 2) void gemm_stats_f16(
    const _Float16* __restrict__ Xh, const _Float16* __restrict__ Wh,
    const float* __restrict__ bias,
    float* __restrict__ pmax, float* __restrict__ psum,
    float* __restrict__ bsum, int computeSum)
{
  __shared__ unsigned char ldsbuf[131072];
  unsigned char* ldsby = ldsbuf;

  int bid = blockIdx.x;
  int swz = (bid & 7) * (NBLK/8) + (bid >> 3);   // XCD-aware, bijective (1000%8==0)
  int rowt = swz & 7;          // fast axis: 8 row tiles share W panel in L2
  int colt = swz >> 3;         // 125 col tiles
  int brow = rowt * BM;
  int bcol = colt * BN;

  int tid  = threadIdx.x;
  int lane = tid & 63;
  int wv   = tid >> 6;
  int wr   = wv >> 2;          // 0..1 (M)
  int wc   = wv & 3;           // 0..3 (N)
  int l15  = lane & 15;
  int q    = lane >> 4;

  // fragment offsets within a unit (pair-interleaved + XOR swizzle)
  int aswz = (((((l15 & 1) << 2) | q) ^ ((l15 >> 1) & 7)) << 4) + ((l15 >> 1) << 7);
  int aofs[8], bofs[4];
  #pragma unroll
  for (int m = 0; m < 8; m++) aofs[m] = wr*8192 + m*1024 + aswz;
  #pragma unroll
  for (int n = 0; n < 4; n++) bofs[n] = wc*4096 + n*1024 + aswz;

  // staging: linear LDS dest (tid*16 within 8KB chunk), inverse-permuted
  // global source: thread (wv,l) -> pair p = wv*8+(l>>3), s = (l&7)^((l>>3)&7)
  // -> row = 2p+(s>>2), kcol = (s&3)*16
  int s8  = (tid & 7) ^ ((tid >> 3) & 7);
  int rl  = wv*16 + (((tid >> 3) & 7) << 1) + (s8 >> 2);
  int kc  = (s8 & 3) << 4;
  int sA0 = (brow + rl)*(HD*2) + kc;
  int sA1 = sA0 + 128*(HD*2);
  int sB0 = (bcol + rl)*(HD*2) + kc;
  int sB1 = sB0 + 128*(HD*2);
  int ldst0 = (wv << 10);          // wave-uniform LDS dest (+lane*16 by HW)
  int ldst1 = (wv << 10) + 8192;

  const char* Xb = (const char*)Xh;
  const char* Wb = (const char*)Wh;

  float4v acc[8][4];
  #pragma unroll
  for (int m=0;m<8;m++)
    #pragma unroll
    for (int n=0;n<4;n++) acc[m][n] = (float4v){0.f,0.f,0.f,0.f};

  // prologue: tile0 u0..u3 + tile1 u0,u1 (12 loads), wait for tile0's 8
  gload_lds16(Xb + sA0,       ldsby + 0     + ldst0);
  gload_lds16(Xb + sA1,       ldsby + 0     + ldst1);
  gload_lds16(Wb + sB0,       ldsby + 16384 + ldst0);
  gload_lds16(Wb + sB1,       ldsby + 16384 + ldst1);
  gload_lds16(Xb + (sA0+64),  ldsby + 32768 + ldst0);
  gload_lds16(Xb + (sA1+64),  ldsby + 32768 + ldst1);
  gload_lds16(Wb + (sB0+64),  ldsby + 49152 + ldst0);
  gload_lds16(Wb + (sB1+64),  ldsby + 49152 + ldst1);
  gload_lds16(Xb + (sA0+128), ldsby + 65536 + ldst0);
  gload_lds16(Xb + (sA1+128), ldsby + 65536 + ldst1);
  gload_lds16(Wb + (sB0+128), ldsby + 81920 + ldst0);
  gload_lds16(Wb + (sB1+128), ldsby + 81920 + ldst1);
  asm volatile("s_waitcnt vmcnt(4)" ::: "memory");
  __builtin_amdgcn_s_barrier();

  int kbn = 128;   // byte k-offset of tile t+1 when processing tile t
  #pragma unroll 1
  for (int i = 0; i < 15; ++i) {
    ktile<0,     true, true, 4>(ldsby, Xb, Wb, sA0,sA1,sB0,sB1, ldst0,ldst1, kbn, aofs, bofs, acc);
    kbn += 128;
    ktile<65536, true, true, 4>(ldsby, Xb, Wb, sA0,sA1,sB0,sB1, ldst0,ldst1, kbn, aofs, bofs, acc);
    kbn += 128;
  }
  // tiles 30, 31
  ktile<0,     true,  false, 0>(ldsby, Xb, Wb, sA0,sA1,sB0,sB1, ldst0,ldst1, kbn, aofs, bofs, acc);
  kbn += 128;
  ktile<65536, false, false, -1>(ldsby, Xb, Wb, sA0,sA1,sB0,sB1, ldst0,ldst1, kbn, aofs, bofs, acc);

  // ---------------- epilogue: bias + per-row max/sumexp ----------------
  float bv[4];
  #pragma unroll
  for (int n=0;n<4;n++) bv[n] = bias[bcol + wc*64 + n*16 + l15];

  float lsum = 0.f;
  int ch = colt*4 + wc;
  #pragma unroll
  for (int m=0;m<8;m++) {
    #pragma unroll
    for (int r=0;r<4;r++) {
      float v0 = acc[m][0][r] + bv[0];
      float v1 = acc[m][1][r] + bv[1];
      float v2 = acc[m][2][r] + bv[2];
      float v3 = acc[m][3][r] + bv[3];
      if (computeSum) lsum += v0+v1+v2+v3;
      float mx = fmaxf(fmaxf(v0,v1), fmaxf(v2,v3));
      #pragma unroll
      for (int off=1; off<16; off<<=1) mx = fmaxf(mx, __shfl_xor(mx, off, 64));
      float se = __expf(v0-mx)+__expf(v1-mx)+__expf(v2-mx)+__expf(v3-mx);
      #pragma unroll
      for (int off=1; off<16; off<<=1) se += __shfl_xor(se, off, 64);
      if (l15 == 0) {
        int row = brow + wr*128 + m*16 + (lane>>4)*4 + r;
        pmax[(size_t)row*NCH + ch] = mx;
        psum[(size_t)row*NCH + ch] = se;
      }
    }
  }

  if (computeSum) {
    #pragma unroll
    for (int off=1; off<64; off<<=1) lsum += __shfl_xor(lsum, off, 64);
    __syncthreads();
    float* red = (float*)ldsbuf;
    if (lane == 0) red[wv] = lsum;
    __syncthreads();
    if (tid == 0) {
      float s = 0.f;
      for (int w=0; w<8; w++) s += red[w];
      bsum[blockIdx.x] = s;
    }
  }
}

// ---------- per-row combine ----------
__global__ void row_combine(const float* __restrict__ pmax,
                            const float* __restrict__ psum,
                            const float* __restrict__ mask,
                            float* __restrict__ tok)
{
  int row = blockIdx.x;
  int lane = threadIdx.x;
  float M = -INFINITY;
  for (int c = lane; c < NCH; c += 64) M = fmaxf(M, pmax[(size_t)row*NCH + c]);
  #pragma unroll
  for (int off=1; off<64; off<<=1) M = fmaxf(M, __shfl_xor(M, off, 64));
  float L = 0.f;
  for (int c = lane; c < NCH; c += 64)
    L += psum[(size_t)row*NCH + c] * __expf(pmax[(size_t)row*NCH + c] - M);
  #pragma unroll
  for (int off=1; off<64; off<<=1) L += __shfl_xor(L, off, 64);
  if (lane == 0) tok[row] = -logf(L) * mask[row];
}

// ---------- finalize ----------
__global__ void finalize(const float* __restrict__ tokP,
                         const float* __restrict__ tokR,
                         const float* __restrict__ rewards,
                         const float* __restrict__ bsum, int nbsum,
                         float* __restrict__ out)
{
  __shared__ float red[256];
  __shared__ float seqP[4], seqR[4];
  int t = threadIdx.x;
  for (int b=0; b<4; b++) {
    float v = tokP[b*512 + t] + tokP[b*512 + 256 + t];
    red[t] = v; __syncthreads();
    for (int s=128; s>0; s>>=1) { if (t < s) red[t] += red[t+s]; __syncthreads(); }
    if (t == 0) seqP[b] = red[0];
    __syncthreads();
    v = tokR[b*512 + t] + tokR[b*512 + 256 + t];
    red[t] = v; __syncthreads();
    for (int s=128; s>0; s>>=1) { if (t < s) red[t] += red[t+s]; __syncthreads(); }
    if (t == 0) seqR[b] = red[0];
    __syncthreads();
  }
  float ls = 0.f;
  for (int i=t; i<nbsum; i+=256) ls += bsum[i];
  red[t] = ls; __syncthreads();
  for (int s=128; s>0; s>>=1) { if (t < s) red[t] += red[t+s]; __syncthreads(); }
  if (t == 0) {
    float r0=rewards[0], r1=rewards[1], r2=rewards[2], r3=rewards[3];
    float rm = (r0+r1+r2+r3)*0.25f;
    float var = ((r0-rm)*(r0-rm)+(r1-rm)*(r1-rm)+(r2-rm)*(r2-rm)+(r3-rm)*(r3-rm))/3.f;
    float rstd = sqrtf(var);
    float adv[4] = {r0-rm, r1-rm, r2-rm, r3-rm};
    if (rstd > 0.f) { for (int b=0;b<4;b++) adv[b] /= rstd; }
    float loss=0.f, sm=0.f, km=0.f;
    for (int b=0;b<4;b++) {
      float kl = seqP[b] - seqR[b];
      loss += -(adv[b]*seqP[b]) + 0.1f*kl;
      sm += seqP[b]; km += kl;
    }
    loss *= 0.25f; sm *= 0.25f; km *= 0.25f;
    float sv = 0.f;
    for (int b=0;b<4;b++) { float d = seqP[b]-sm; sv += d*d; }
    float sstd = sqrtf(sv/3.f);
    out[0] = loss;
    out[1] = sm;
    out[2] = sstd;
    out[3] = red[0] / ((float)TOK * (float)VOC);
    out[4] = km;
  }
}

extern "C" void kernel_launch(void* const* d_in, const int* in_sizes, int n_in,
                              void* d_out, int out_size, void* d_ws, size_t ws_size,
                              hipStream_t stream) {
  const float* W    = (const float*)d_in[0];
  const float* X    = (const float*)d_in[1];
  const float* mask = (const float*)d_in[2];
  const float* rew  = (const float*)d_in[3];
  const float* bias = (const float*)d_in[4];
  const float* Xr   = (const float*)d_in[5];
  const float* Wr   = (const float*)d_in[6];
  const float* br   = (const float*)d_in[7];
  float* out = (float*)d_out;

  float* pmax = (float*)d_ws;                       // 2048*500
  float* psum = pmax + (size_t)TOK*NCH;             // 2048*500
  float* tokP = psum + (size_t)TOK*NCH;             // 2048
  float* tokR = tokP + TOK;                         // 2048
  float* bsum = tokR + TOK;                         // 4096 (pad)

  size_t headFloats = (size_t)TOK*NCH*2 + TOK*2 + 4096;
  size_t offXh = headFloats * 4;
  _Float16* Xh = (_Float16*)((unsigned char*)d_ws + offXh);
  _Float16* Wh = (_Float16*)((unsigned char*)d_ws + offXh + (size_t)TOK*HD*2);

  cvt_f32_f16<<<2048, 256, 0, stream>>>(X,  Xh, TOK*HD/8);
  cvt_f32_f16<<<2048, 256, 0, stream>>>(W,  Wh, VOC*HD/8);
  gemm_stats_f16<<<NBLK, 512, 0, stream>>>(Xh, Wh, bias, pmax, psum, bsum, 1);
  row_combine<<<TOK, 64, 0, stream>>>(pmax, psum, mask, tokP);
  cvt_f32_f16<<<2048, 256, 0, stream>>>(Xr, Xh, TOK*HD/8);
  cvt_f32_f16<<<2048, 256, 0, stream>>>(Wr, Wh, VOC*HD/8);
  gemm_stats_f16<<<NBLK, 512, 0, stream>>>(Xh, Wh, br, pmax, psum, bsum, 0);
  row_combine<<<TOK, 64, 0, stream>>>(pmax, psum, mask, tokR);
  finalize<<<1, 256, 0, stream>>>(tokP, tokR, rew, bsum, NBLK, out);
}